// Round 5
// baseline (1740.736 us; speedup 1.0000x reference)
//
#include <hip/hip_runtime.h>
#include <cmath>

#define E_ 64
#define H_ 4
#define B_ 2
#define R_ 1225
#define C_ 512
#define EPS 1e-5f

__device__ __forceinline__ float elu1(float a) { return a > 0.f ? a + 1.f : __expf(a); }

typedef float f32x4 __attribute__((ext_vector_type(4)));
typedef short bf16x8 __attribute__((ext_vector_type(8)));
typedef short bf16x4 __attribute__((ext_vector_type(4)));

__device__ __forceinline__ unsigned short f2bf(float f) {
    union { float f; unsigned u; } c; c.f = f;
    unsigned u = c.u + 0x7FFFu + ((c.u >> 16) & 1u);   // RNE
    return (unsigned short)(u >> 16);
}

__device__ __forceinline__ float bf2f(unsigned short s) {
    union { unsigned u; float f; } c; c.u = ((unsigned)s) << 16;
    return c.f;
}

__device__ __forceinline__ bf16x8 pack8(float4 a, float4 b) {
    bf16x8 r;
    r[0] = (short)f2bf(a.x); r[1] = (short)f2bf(a.y);
    r[2] = (short)f2bf(a.z); r[3] = (short)f2bf(a.w);
    r[4] = (short)f2bf(b.x); r[5] = (short)f2bf(b.y);
    r[6] = (short)f2bf(b.z); r[7] = (short)f2bf(b.w);
    return r;
}

// tanh-approx GELU in sigmoid form (max dev ~3e-4 vs exact-erf)
__device__ __forceinline__ float gelu_fast(float a) {
    const float u = a * (-1.5957691216057308f - 0.0713548162726009f * a * a);
    return a / (1.f + __expf(u));
}

#define SX 264   // s_xnT row stride (256+8) in bf16

// ---------------------------------------------------------------------------
// Kernel A: row attention over c (C=512) for each (b, r).
// 256 thr, 2 tiles. VGPR-lean: xn fused (never an array), s_kb 4 rows only.
// LDS ~38.4KB -> 4 blocks/CU; launch_bounds(256,4) pins VGPR<=128.
// ---------------------------------------------------------------------------
__global__ __launch_bounds__(256, 4) void row_attn(
    const float* __restrict__ x,
    const float* __restrict__ wq, const float* __restrict__ bq,
    const float* __restrict__ wk, const float* __restrict__ bk,
    const float* __restrict__ wv, const float* __restrict__ bv,
    const float* __restrict__ wo, const float* __restrict__ bo,
    const float* __restrict__ lng, const float* __restrict__ lnb,
    float* __restrict__ hout)
{
    const int r = blockIdx.x;
    const int b = blockIdx.y;
    const int t = threadIdx.x;
    const int w = t >> 6;
    const int l = t & 63;
    const int lr = l & 15;
    const int lq = l >> 4;

    __shared__ short s_xnT[E_][SX];
    __shared__ short s_kb[4][SX];
    __shared__ float s_u[H_][E_];
    __shared__ float s_ktv[E_];
    __shared__ float s_wok[E_][H_];
    __shared__ float s_qm[H_];
    __shared__ float s_sk[H_];
    __shared__ float red_q[4][H_];
    __shared__ float red_k[4][H_];

    const size_t RC = (size_t)R_ * C_;
    const float* xbase = x + (size_t)b * E_ * RC + (size_t)r * C_;

    float aq[H_] = {0.f, 0.f, 0.f, 0.f};
    float ak[H_] = {0.f, 0.f, 0.f, 0.f};
    float qs[2][H_];
    f32x4 uacc; uacc[0] = uacc[1] = uacc[2] = uacc[3] = 0.f;

    #pragma unroll
    for (int it = 0; it < 2; ++it) {
        const int c = it * 256 + t;
        const float* xp = xbase + c;
        float xv[E_];
        #pragma unroll
        for (int e = 0; e < E_; ++e) xv[e] = xp[(size_t)e * RC];
        float s = 0.f, ss = 0.f;
        #pragma unroll
        for (int e = 0; e < E_; ++e) { s += xv[e]; ss += xv[e] * xv[e]; }
        const float mu = s * (1.f / E_);
        const float rstd = rsqrtf(ss * (1.f / E_) - mu * mu + EPS);

        float tq[H_], tk[H_];
        #pragma unroll
        for (int h = 0; h < H_; ++h) { tq[h] = bq[h]; tk[h] = bk[h]; }
        // fused: xn per element -> q/k FMA + LDS write; xn never an array
        #pragma unroll
        for (int e = 0; e < E_; ++e) {
            const float xn = (xv[e] - mu) * rstd * lng[e] + lnb[e];
            #pragma unroll
            for (int h = 0; h < H_; ++h) { tq[h] += xn * wq[h * E_ + e]; tk[h] += xn * wk[h * E_ + e]; }
            s_xnT[e][t] = (short)f2bf(xn);
        }
        #pragma unroll
        for (int h = 0; h < H_; ++h) {
            const float qv = elu1(tq[h]);
            const float kv = elu1(tk[h]);
            qs[it][h] = qv;
            aq[h] += qv; ak[h] += kv;
            s_kb[h][t] = (short)f2bf(kv);
        }
        __syncthreads();
        #pragma unroll
        for (int ks = 0; ks < 8; ++ks) {
            bf16x8 af;
            #pragma unroll
            for (int i = 0; i < 8; ++i) af[i] = 0;
            if (lr < 4) af = *reinterpret_cast<const bf16x8*>(&s_kb[lr][ks * 32 + lq * 8]);
            const bf16x8 bf = *reinterpret_cast<const bf16x8*>(&s_xnT[w * 16 + lr][ks * 32 + lq * 8]);
            uacc = __builtin_amdgcn_mfma_f32_16x16x32_bf16(af, bf, uacc, 0, 0, 0);
        }
        __syncthreads();
    }

    if (lq == 0) {
        #pragma unroll
        for (int i = 0; i < 4; ++i) s_u[i][w * 16 + lr] = uacc[i];
    }
    #pragma unroll
    for (int h = 0; h < H_; ++h) {
        #pragma unroll
        for (int off = 32; off; off >>= 1) { aq[h] += __shfl_xor(aq[h], off, 64); ak[h] += __shfl_xor(ak[h], off, 64); }
    }
    if (l == 0) {
        #pragma unroll
        for (int h = 0; h < H_; ++h) { red_q[w][h] = aq[h]; red_k[w][h] = ak[h]; }
    }
    __syncthreads();
    if (t < H_) {
        float sq = 0.f, sk = 0.f;
        #pragma unroll
        for (int w2 = 0; w2 < 4; ++w2) { sq += red_q[w2][t]; sk += red_k[w2][t]; }
        s_qm[t] = sq * (1.f / C_);
        s_sk[t] = sk;
    }
    __syncthreads();
    if (t < E_) {
        const int h = t >> 4;
        float acc = 0.f;
        #pragma unroll
        for (int e = 0; e < E_; ++e) acc += wv[t * E_ + e] * s_u[h][e];
        s_ktv[t] = acc / s_sk[h] + bv[t];
    }
    __syncthreads();
    if (t < E_) {
        #pragma unroll
        for (int h = 0; h < H_; ++h) {
            float acc = 0.f;
            #pragma unroll
            for (int d = 0; d < 16; ++d) acc += wo[t * E_ + h * 16 + d] * s_ktv[h * 16 + d];
            s_wok[t][h] = acc;
        }
    }
    __syncthreads();

    #pragma unroll
    for (int it = 0; it < 2; ++it) {
        const int c = it * 256 + t;
        const float* xp = xbase + c;
        float qn[H_];
        #pragma unroll
        for (int h = 0; h < H_; ++h) qn[h] = qs[it][h] / s_qm[h];
        float* hp = hout + ((size_t)(b * C_ + c) * R_ + r) * E_;
        #pragma unroll
        for (int e4 = 0; e4 < 16; ++e4) {
            float4 o;
            float* ov = (float*)&o;
            #pragma unroll
            for (int i = 0; i < 4; ++i) {
                const int e = e4 * 4 + i;
                float tt = bo[e];
                #pragma unroll
                for (int h = 0; h < H_; ++h) tt += qn[h] * s_wok[e][h];
                ov[i] = xp[(size_t)e * RC] + tt;
            }
            *reinterpret_cast<float4*>(hp + e4 * 4) = o;
        }
    }
}

// ---------------------------------------------------------------------------
// Kernel B: col attention over r (R=1225) for each (b, c). In-place.
// Same VGPR-lean treatment; qs packed to bf16 pairs (10 regs not 20).
// ---------------------------------------------------------------------------
__global__ __launch_bounds__(256, 4) void col_attn(
    float* __restrict__ hbuf,
    const float* __restrict__ wq, const float* __restrict__ bq,
    const float* __restrict__ wk, const float* __restrict__ bk,
    const float* __restrict__ wv, const float* __restrict__ bv,
    const float* __restrict__ wo, const float* __restrict__ bo,
    const float* __restrict__ lng, const float* __restrict__ lnb)
{
    const int c = blockIdx.x;
    const int b = blockIdx.y;
    const int t = threadIdx.x;
    const int w = t >> 6;
    const int l = t & 63;
    const int lr = l & 15;
    const int lq = l >> 4;

    __shared__ short s_xnT[E_][SX];
    __shared__ short s_kb[4][SX];
    __shared__ float s_u[H_][E_];
    __shared__ float s_ktv[E_];
    __shared__ float s_wok[E_][H_];
    __shared__ float s_qm[H_];
    __shared__ float s_sk[H_];
    __shared__ float red_q[4][H_];
    __shared__ float red_k[4][H_];

    float* hp0 = hbuf + (size_t)(b * C_ + c) * R_ * E_;

    float aq[H_] = {0.f, 0.f, 0.f, 0.f};
    float ak[H_] = {0.f, 0.f, 0.f, 0.f};
    unsigned qs_pk[5][2];              // q as packed bf16 pairs (h0|h1, h2|h3)
    f32x4 uacc; uacc[0] = uacc[1] = uacc[2] = uacc[3] = 0.f;

    #pragma unroll
    for (int it = 0; it < 5; ++it) {
        const int rr = it * 256 + t;
        const bool valid = (rr < R_);
        if (valid) {
            const float* pp = hp0 + (size_t)rr * E_;
            float hv[E_];
            #pragma unroll
            for (int e4 = 0; e4 < 16; ++e4) {
                const float4 v4 = *reinterpret_cast<const float4*>(pp + e4 * 4);
                hv[e4 * 4 + 0] = v4.x; hv[e4 * 4 + 1] = v4.y;
                hv[e4 * 4 + 2] = v4.z; hv[e4 * 4 + 3] = v4.w;
            }
            float s = 0.f, ss = 0.f;
            #pragma unroll
            for (int e = 0; e < E_; ++e) { s += hv[e]; ss += hv[e] * hv[e]; }
            const float mu = s * (1.f / E_);
            const float rstd = rsqrtf(ss * (1.f / E_) - mu * mu + EPS);
            float tq[H_], tk[H_];
            #pragma unroll
            for (int h = 0; h < H_; ++h) { tq[h] = bq[h]; tk[h] = bk[h]; }
            #pragma unroll
            for (int e = 0; e < E_; ++e) {
                const float xn = (hv[e] - mu) * rstd * lng[e] + lnb[e];
                #pragma unroll
                for (int h = 0; h < H_; ++h) { tq[h] += xn * wq[h * E_ + e]; tk[h] += xn * wk[h * E_ + e]; }
                s_xnT[e][t] = (short)f2bf(xn);
            }
            float qv[H_];
            #pragma unroll
            for (int h = 0; h < H_; ++h) {
                qv[h] = elu1(tq[h]);
                const float kv = elu1(tk[h]);
                aq[h] += qv[h]; ak[h] += kv;
                s_kb[h][t] = (short)f2bf(kv);
            }
            qs_pk[it][0] = ((unsigned)f2bf(qv[1]) << 16) | f2bf(qv[0]);
            qs_pk[it][1] = ((unsigned)f2bf(qv[3]) << 16) | f2bf(qv[2]);
        } else {
            #pragma unroll
            for (int e = 0; e < E_; ++e) s_xnT[e][t] = 0;
            #pragma unroll
            for (int h = 0; h < H_; ++h) s_kb[h][t] = 0;
            qs_pk[it][0] = 0; qs_pk[it][1] = 0;
        }
        __syncthreads();
        #pragma unroll
        for (int ks = 0; ks < 8; ++ks) {
            bf16x8 af;
            #pragma unroll
            for (int i = 0; i < 8; ++i) af[i] = 0;
            if (lr < 4) af = *reinterpret_cast<const bf16x8*>(&s_kb[lr][ks * 32 + lq * 8]);
            const bf16x8 bf = *reinterpret_cast<const bf16x8*>(&s_xnT[w * 16 + lr][ks * 32 + lq * 8]);
            uacc = __builtin_amdgcn_mfma_f32_16x16x32_bf16(af, bf, uacc, 0, 0, 0);
        }
        __syncthreads();
    }

    if (lq == 0) {
        #pragma unroll
        for (int i = 0; i < 4; ++i) s_u[i][w * 16 + lr] = uacc[i];
    }
    #pragma unroll
    for (int h = 0; h < H_; ++h) {
        #pragma unroll
        for (int off = 32; off; off >>= 1) { aq[h] += __shfl_xor(aq[h], off, 64); ak[h] += __shfl_xor(ak[h], off, 64); }
    }
    if (l == 0) {
        #pragma unroll
        for (int h = 0; h < H_; ++h) { red_q[w][h] = aq[h]; red_k[w][h] = ak[h]; }
    }
    __syncthreads();
    if (t < H_) {
        float sq = 0.f, sk = 0.f;
        #pragma unroll
        for (int w2 = 0; w2 < 4; ++w2) { sq += red_q[w2][t]; sk += red_k[w2][t]; }
        s_qm[t] = sq * (1.f / R_);
        s_sk[t] = sk;
    }
    __syncthreads();
    if (t < E_) {
        const int h = t >> 4;
        float acc = 0.f;
        #pragma unroll
        for (int e = 0; e < E_; ++e) acc += wv[t * E_ + e] * s_u[h][e];
        s_ktv[t] = acc / s_sk[h] + bv[t];
    }
    __syncthreads();
    if (t < E_) {
        #pragma unroll
        for (int h = 0; h < H_; ++h) {
            float acc = 0.f;
            #pragma unroll
            for (int d = 0; d < 16; ++d) acc += wo[t * E_ + h * 16 + d] * s_ktv[h * 16 + d];
            s_wok[t][h] = acc;
        }
    }
    __syncthreads();

    #pragma unroll
    for (int it = 0; it < 5; ++it) {
        const int rr = it * 256 + t;
        if (rr >= R_) continue;
        float qn[H_];
        qn[0] = bf2f((unsigned short)(qs_pk[it][0] & 0xFFFF)) / s_qm[0];
        qn[1] = bf2f((unsigned short)(qs_pk[it][0] >> 16))    / s_qm[1];
        qn[2] = bf2f((unsigned short)(qs_pk[it][1] & 0xFFFF)) / s_qm[2];
        qn[3] = bf2f((unsigned short)(qs_pk[it][1] >> 16))    / s_qm[3];
        float* pp = hp0 + (size_t)rr * E_;
        #pragma unroll
        for (int e4 = 0; e4 < 16; ++e4) {
            const float4 v4 = *reinterpret_cast<const float4*>(pp + e4 * 4);
            const float* hv4 = (const float*)&v4;
            float4 o;
            float* ov = (float*)&o;
            #pragma unroll
            for (int i = 0; i < 4; ++i) {
                const int e = e4 * 4 + i;
                float tt = bo[e];
                #pragma unroll
                for (int h = 0; h < H_; ++h) tt += qn[h] * s_wok[e][h];
                ov[i] = hv4[i] + tt;
            }
            *reinterpret_cast<float4*>(pp + e4 * 4) = o;
        }
    }
}

// ---------------------------------------------------------------------------
// prep_weights: fp32 -> bf16 for w1/w2 (unchanged).
// ---------------------------------------------------------------------------
__global__ __launch_bounds__(256) void prep_weights(
    const float* __restrict__ w1, const float* __restrict__ w2,
    short* __restrict__ w1b, short* __restrict__ w2b)
{
    const int i = blockIdx.x * 256 + threadIdx.x;
    if (i < 16384) w1b[i] = (short)f2bf(w1[i]);
    else           w2b[i - 16384] = (short)f2bf(w2[i - 16384]);
}

// ---------------------------------------------------------------------------
// Kernel C: MFMA bf16 FFN (unchanged from round 4).
// ---------------------------------------------------------------------------
#define SA 72
#define SG 264
#define SO 65

template <bool PREP>
__global__ __launch_bounds__(256) void ffn_mfma(
    const float* __restrict__ hbuf,
    const float* __restrict__ lng, const float* __restrict__ lnb,
    const float* __restrict__ w1, const short* __restrict__ w1b,
    const float* __restrict__ b1,
    const float* __restrict__ w2, const short* __restrict__ w2b,
    const float* __restrict__ b2,
    float* __restrict__ out)
{
    __shared__ __align__(16) char smem[33792 + 16640];
    short* s_g = (short*)smem;
    short* s_a = (short*)(smem + 33792);
    float* s_o = (float*)(smem + 33792);

    const int t = threadIdx.x;
    const int w = t >> 6;
    const int l = t & 63;
    const int lr = l & 15;
    const int lq = l >> 4;

    const int bid = blockIdx.x;
    const int cb  = bid & 7;
    const int rem = bid >> 3;
    const int r   = rem % R_;
    const int b   = rem / R_;
    const int c0  = cb * 64;

    {
        const int m  = t >> 2;
        const int qi = t & 3;
        const float* hp = hbuf + ((size_t)(b * C_ + c0 + m) * R_ + r) * E_ + qi * 16;
        const float4* hp4 = (const float4*)hp;
        float4 v0 = hp4[0], v1 = hp4[1], v2 = hp4[2], v3 = hp4[3];
        float hv[16];
        hv[0]=v0.x; hv[1]=v0.y; hv[2]=v0.z; hv[3]=v0.w;
        hv[4]=v1.x; hv[5]=v1.y; hv[6]=v1.z; hv[7]=v1.w;
        hv[8]=v2.x; hv[9]=v2.y; hv[10]=v2.z; hv[11]=v2.w;
        hv[12]=v3.x; hv[13]=v3.y; hv[14]=v3.z; hv[15]=v3.w;
        float s = 0.f, ss = 0.f;
        #pragma unroll
        for (int i = 0; i < 16; ++i) { s += hv[i]; ss += hv[i] * hv[i]; }
        s  += __shfl_xor(s, 1, 64);  s  += __shfl_xor(s, 2, 64);
        ss += __shfl_xor(ss, 1, 64); ss += __shfl_xor(ss, 2, 64);
        const float mu = s * (1.f / 64.f);
        const float rstd = rsqrtf(ss * (1.f / 64.f) - mu * mu + EPS);
        bf16x8 o0, o1;
        #pragma unroll
        for (int i = 0; i < 8; ++i) {
            const int e = qi * 16 + i;
            o0[i] = (short)f2bf((hv[i] - mu) * rstd * lng[e] + lnb[e]);
        }
        #pragma unroll
        for (int i = 0; i < 8; ++i) {
            const int e = qi * 16 + 8 + i;
            o1[i] = (short)f2bf((hv[8 + i] - mu) * rstd * lng[e] + lnb[e]);
        }
        *reinterpret_cast<bf16x8*>(&s_a[m * SA + qi * 16])     = o0;
        *reinterpret_cast<bf16x8*>(&s_a[m * SA + qi * 16 + 8]) = o1;
    }
    __syncthreads();

    {
        bf16x8 bfr[4][2];
        #pragma unroll
        for (int mt = 0; mt < 4; ++mt)
            #pragma unroll
            for (int ks = 0; ks < 2; ++ks)
                bfr[mt][ks] = *reinterpret_cast<const bf16x8*>(
                    &s_a[(mt * 16 + lr) * SA + ks * 32 + lq * 8]);

        #pragma unroll
        for (int nn = 0; nn < 4; ++nn) {
            const int jt = w * 4 + nn;
            bf16x8 afr[2];
            if (PREP) {
                #pragma unroll
                for (int ks = 0; ks < 2; ++ks)
                    afr[ks] = *reinterpret_cast<const bf16x8*>(
                        w1b + (size_t)(jt * 16 + lr) * 64 + ks * 32 + lq * 8);
            } else {
                #pragma unroll
                for (int ks = 0; ks < 2; ++ks) {
                    const float4* wp = (const float4*)(w1 + (size_t)(jt * 16 + lr) * 64 + ks * 32 + lq * 8);
                    afr[ks] = pack8(wp[0], wp[1]);
                }
            }
            f32x4 acc[4];
            #pragma unroll
            for (int mt = 0; mt < 4; ++mt) { acc[mt][0]=0.f; acc[mt][1]=0.f; acc[mt][2]=0.f; acc[mt][3]=0.f; }
            #pragma unroll
            for (int ks = 0; ks < 2; ++ks)
                #pragma unroll
                for (int mt = 0; mt < 4; ++mt)
                    acc[mt] = __builtin_amdgcn_mfma_f32_16x16x32_bf16(afr[ks], bfr[mt][ks], acc[mt], 0, 0, 0);

            const float4 b1v = *reinterpret_cast<const float4*>(&b1[jt * 16 + lq * 4]);
            const float* b1p = (const float*)&b1v;
            #pragma unroll
            for (int mt = 0; mt < 4; ++mt) {
                const int m = mt * 16 + lr;
                bf16x4 pk;
                #pragma unroll
                for (int i = 0; i < 4; ++i) {
                    const float aa = acc[mt][i] + b1p[i];
                    pk[i] = (short)f2bf(gelu_fast(aa));
                }
                *reinterpret_cast<bf16x4*>(&s_g[m * SG + jt * 16 + lq * 4]) = pk;
            }
        }
    }
    __syncthreads();

    {
        f32x4 acc2[4];
        #pragma unroll
        for (int mt = 0; mt < 4; ++mt) { acc2[mt][0]=0.f; acc2[mt][1]=0.f; acc2[mt][2]=0.f; acc2[mt][3]=0.f; }
        const int n = w * 16 + lr;
        #pragma unroll
        for (int ks = 0; ks < 8; ++ks) {
            bf16x8 bfr;
            if (PREP) {
                bfr = *reinterpret_cast<const bf16x8*>(w2b + (size_t)n * 256 + ks * 32 + lq * 8);
            } else {
                const float4* wp = (const float4*)(w2 + (size_t)n * 256 + ks * 32 + lq * 8);
                bfr = pack8(wp[0], wp[1]);
            }
            #pragma unroll
            for (int mt = 0; mt < 4; ++mt) {
                const bf16x8 af = *reinterpret_cast<const bf16x8*>(
                    &s_g[(mt * 16 + lr) * SG + ks * 32 + lq * 8]);
                acc2[mt] = __builtin_amdgcn_mfma_f32_16x16x32_bf16(af, bfr, acc2[mt], 0, 0, 0);
            }
        }
        #pragma unroll
        for (int mt = 0; mt < 4; ++mt)
            #pragma unroll
            for (int i = 0; i < 4; ++i)
                s_o[(mt * 16 + lq * 4 + i) * SO + n] = acc2[mt][i];
    }
    __syncthreads();

    {
        const int m  = t & 63;
        const int eb = (t >> 6) * 16;
        const int c  = c0 + m;
        const float* hp = hbuf + ((size_t)(b * C_ + c) * R_ + r) * E_ + eb;
        const float4* hp4 = (const float4*)hp;
        float4 v0 = hp4[0], v1 = hp4[1], v2 = hp4[2], v3 = hp4[3];
        float hv[16];
        hv[0]=v0.x; hv[1]=v0.y; hv[2]=v0.z; hv[3]=v0.w;
        hv[4]=v1.x; hv[5]=v1.y; hv[6]=v1.z; hv[7]=v1.w;
        hv[8]=v2.x; hv[9]=v2.y; hv[10]=v2.z; hv[11]=v2.w;
        hv[12]=v3.x; hv[13]=v3.y; hv[14]=v3.z; hv[15]=v3.w;
        #pragma unroll
        for (int i = 0; i < 16; ++i) {
            const int e = eb + i;
            const float val = s_o[m * SO + e] + b2[e] + hv[i];
            out[(((size_t)b * E_ + e) * R_ + r) * C_ + c] = val;
        }
    }
}

extern "C" void kernel_launch(void* const* d_in, const int* in_sizes, int n_in,
                              void* d_out, int out_size, void* d_ws, size_t ws_size,
                              hipStream_t stream) {
    const float* x      = (const float*)d_in[0];
    const float* row_wq = (const float*)d_in[1];
    const float* row_bq = (const float*)d_in[2];
    const float* row_wk = (const float*)d_in[3];
    const float* row_bk = (const float*)d_in[4];
    const float* row_wv = (const float*)d_in[5];
    const float* row_bv = (const float*)d_in[6];
    const float* row_wo = (const float*)d_in[7];
    const float* row_bo = (const float*)d_in[8];
    const float* col_wq = (const float*)d_in[9];
    const float* col_bq = (const float*)d_in[10];
    const float* col_wk = (const float*)d_in[11];
    const float* col_bk = (const float*)d_in[12];
    const float* col_wv = (const float*)d_in[13];
    const float* col_bv = (const float*)d_in[14];
    const float* col_wo = (const float*)d_in[15];
    const float* col_bo = (const float*)d_in[16];
    const float* rn_g   = (const float*)d_in[17];
    const float* rn_b   = (const float*)d_in[18];
    const float* cn_g   = (const float*)d_in[19];
    const float* cn_b   = (const float*)d_in[20];
    const float* fn_g   = (const float*)d_in[21];
    const float* fn_b   = (const float*)d_in[22];
    const float* w1     = (const float*)d_in[23];
    const float* b1     = (const float*)d_in[24];
    const float* w2     = (const float*)d_in[25];
    const float* b2     = (const float*)d_in[26];

    const size_t need = (size_t)B_ * C_ * R_ * E_ * sizeof(float);
    if (ws_size < need) return;
    float* hbuf = (float*)d_ws;

    const bool prep = (ws_size >= need + 2 * 16384 * sizeof(short) + 256);
    short* w1b = (short*)((char*)d_ws + need);
    short* w2b = w1b + 16384;

    row_attn<<<dim3(R_, B_), 256, 0, stream>>>(
        x, row_wq, row_bq, row_wk, row_bk, row_wv, row_bv, row_wo, row_bo,
        rn_g, rn_b, hbuf);
    col_attn<<<dim3(C_, B_), 256, 0, stream>>>(
        hbuf, col_wq, col_bq, col_wk, col_bk, col_wv, col_bv, col_wo, col_bo,
        cn_g, cn_b);
    if (prep) {
        prep_weights<<<128, 256, 0, stream>>>(w1, w2, w1b, w2b);
        ffn_mfma<true><<<B_ * R_ * 8, 256, 0, stream>>>(
            hbuf, fn_g, fn_b, w1, w1b, b1, w2, w2b, b2, (float*)d_out);
    } else {
        ffn_mfma<false><<<B_ * R_ * 8, 256, 0, stream>>>(
            hbuf, fn_g, fn_b, w1, w1b, b1, w2, w2b, b2, (float*)d_out);
    }
}

// Round 6
// 1405.435 us; speedup vs baseline: 1.2386x; 1.2386x over previous
//
#include <hip/hip_runtime.h>
#include <cmath>

#define E_ 64
#define H_ 4
#define B_ 2
#define R_ 1225
#define C_ 512
#define EPS 1e-5f

__device__ __forceinline__ float elu1(float a) { return a > 0.f ? a + 1.f : __expf(a); }

typedef float f32x4 __attribute__((ext_vector_type(4)));
typedef short bf16x8 __attribute__((ext_vector_type(8)));
typedef short bf16x4 __attribute__((ext_vector_type(4)));

__device__ __forceinline__ unsigned short f2bf(float f) {
    union { float f; unsigned u; } c; c.f = f;
    unsigned u = c.u + 0x7FFFu + ((c.u >> 16) & 1u);   // RNE
    return (unsigned short)(u >> 16);
}

__device__ __forceinline__ float bf2f(unsigned short s) {
    union { unsigned u; float f; } c; c.u = ((unsigned)s) << 16;
    return c.f;
}

__device__ __forceinline__ bf16x8 pack8(float4 a, float4 b) {
    bf16x8 r;
    r[0] = (short)f2bf(a.x); r[1] = (short)f2bf(a.y);
    r[2] = (short)f2bf(a.z); r[3] = (short)f2bf(a.w);
    r[4] = (short)f2bf(b.x); r[5] = (short)f2bf(b.y);
    r[6] = (short)f2bf(b.z); r[7] = (short)f2bf(b.w);
    return r;
}

// tanh-approx GELU in sigmoid form (max dev ~3e-4 vs exact-erf)
__device__ __forceinline__ float gelu_fast(float a) {
    const float u = a * (-1.5957691216057308f - 0.0713548162726009f * a * a);
    return a / (1.f + __expf(u));
}

#define SX 264   // LDS row stride (256+8) in bf16

// ---------------------------------------------------------------------------
// Attention math (both kernels): LN is per-position affine, so
//   q_pre[h] = rstd*dq[h] - rstd*mu*WgQ[h] + CQ[h] + bq[h],  dq = sum wq*g*xv
//   u[h][e]  = g[e]*(M1[h][e] - S1[h]) + lb[e]*sk[h]
//   M1[h][e] = sum_c (k_c*rstd_c) * xv[c,e]   (MFMA on RAW x, A-rows k*rstd)
//   S1[h]    = sum_c k_c*rstd_c*mu_c,  sk[h] = sum_c k_c
// => no xn/xv arrays in registers, nothing to spill.
// ---------------------------------------------------------------------------

// ---------------------------------------------------------------------------
// Kernel A: row attention over c (C=512) for each (b, r). 256 thr, 2 tiles.
// ---------------------------------------------------------------------------
__global__ __launch_bounds__(256, 4) void row_attn(
    const float* __restrict__ x,
    const float* __restrict__ wq, const float* __restrict__ bq,
    const float* __restrict__ wk, const float* __restrict__ bk,
    const float* __restrict__ wv, const float* __restrict__ bv,
    const float* __restrict__ wo, const float* __restrict__ bo,
    const float* __restrict__ lng, const float* __restrict__ lnb,
    float* __restrict__ hout)
{
    const int r = blockIdx.x;
    const int b = blockIdx.y;
    const int t = threadIdx.x;
    const int w = t >> 6;
    const int l = t & 63;
    const int lr = l & 15;
    const int lq = l >> 4;

    __shared__ short s_xT[E_][SX];     // raw x, bf16, [e][pos-in-tile]
    __shared__ short s_kb[4][SX];      // k*rstd, bf16
    __shared__ float s_u[H_][E_];
    __shared__ float s_ktv[E_];
    __shared__ float s_wok[E_][H_];
    __shared__ float s_qm[H_];
    __shared__ float s_sk[H_];
    __shared__ float s_S1[H_];
    __shared__ float red_q[4][H_];
    __shared__ float red_k[4][H_];
    __shared__ float red_k2[4][H_];
    __shared__ float s_cst[16];        // WgQ[4] CQ[4] WgK[4] CK[4]

    // block-uniform constants
    if (t < 16) {
        const int h = t & 3;
        const int kind = t >> 2;                    // 0 WgQ, 1 CQ, 2 WgK, 3 CK
        const float* wm = (kind < 2) ? wq : wk;
        const float* vm = (kind & 1) ? lnb : lng;
        float acc = 0.f;
        for (int e = 0; e < E_; ++e) acc += wm[h * E_ + e] * vm[e];
        s_cst[t] = acc;
    }
    __syncthreads();

    const size_t RC = (size_t)R_ * C_;
    const float* xbase = x + (size_t)b * E_ * RC + (size_t)r * C_;

    float aq[H_]  = {0.f, 0.f, 0.f, 0.f};
    float ak[H_]  = {0.f, 0.f, 0.f, 0.f};
    float ak2[H_] = {0.f, 0.f, 0.f, 0.f};
    float qs[2][H_];
    f32x4 uacc; uacc[0] = uacc[1] = uacc[2] = uacc[3] = 0.f;

    #pragma unroll
    for (int it = 0; it < 2; ++it) {
        const float* xp = xbase + it * 256 + t;
        float s = 0.f, ss = 0.f;
        float dq[H_] = {0.f, 0.f, 0.f, 0.f};
        float dk[H_] = {0.f, 0.f, 0.f, 0.f};
        #pragma unroll
        for (int e = 0; e < E_; ++e) {
            const float xv = xp[(size_t)e * RC];
            s += xv; ss += xv * xv;
            const float t1 = lng[e] * xv;
            #pragma unroll
            for (int h = 0; h < H_; ++h) { dq[h] += wq[h * E_ + e] * t1; dk[h] += wk[h * E_ + e] * t1; }
            s_xT[e][t] = (short)f2bf(xv);
        }
        const float mu = s * (1.f / E_);
        const float rstd = rsqrtf(ss * (1.f / E_) - mu * mu + EPS);
        const float mr = mu * rstd;
        #pragma unroll
        for (int h = 0; h < H_; ++h) {
            const float qv = elu1(rstd * dq[h] - mr * s_cst[h]     + s_cst[4 + h]  + bq[h]);
            const float kv = elu1(rstd * dk[h] - mr * s_cst[8 + h] + s_cst[12 + h] + bk[h]);
            qs[it][h] = qv;
            aq[h] += qv; ak[h] += kv; ak2[h] += kv * mr;
            s_kb[h][t] = (short)f2bf(kv * rstd);
        }
        __syncthreads();
        #pragma unroll
        for (int ks = 0; ks < 8; ++ks) {
            bf16x8 af;
            #pragma unroll
            for (int i = 0; i < 8; ++i) af[i] = 0;
            if (lr < 4) af = *reinterpret_cast<const bf16x8*>(&s_kb[lr][ks * 32 + lq * 8]);
            const bf16x8 bf = *reinterpret_cast<const bf16x8*>(&s_xT[w * 16 + lr][ks * 32 + lq * 8]);
            uacc = __builtin_amdgcn_mfma_f32_16x16x32_bf16(af, bf, uacc, 0, 0, 0);
        }
        __syncthreads();
    }

    // reductions of sum_q, sum_k, sum k*rstd*mu
    #pragma unroll
    for (int h = 0; h < H_; ++h) {
        #pragma unroll
        for (int off = 32; off; off >>= 1) {
            aq[h] += __shfl_xor(aq[h], off, 64);
            ak[h] += __shfl_xor(ak[h], off, 64);
            ak2[h] += __shfl_xor(ak2[h], off, 64);
        }
    }
    if (l == 0) {
        #pragma unroll
        for (int h = 0; h < H_; ++h) { red_q[w][h] = aq[h]; red_k[w][h] = ak[h]; red_k2[w][h] = ak2[h]; }
    }
    __syncthreads();
    if (t < H_) {
        float sq = 0.f, sk = 0.f, s1 = 0.f;
        #pragma unroll
        for (int w2 = 0; w2 < 4; ++w2) { sq += red_q[w2][t]; sk += red_k[w2][t]; s1 += red_k2[w2][t]; }
        s_qm[t] = sq * (1.f / C_);
        s_sk[t] = sk;
        s_S1[t] = s1;
    }
    __syncthreads();
    // corrected u: u[h][e] = g[e]*(M1 - S1[h]) + lb[e]*sk[h]
    if (lq == 0) {
        const int e = w * 16 + lr;
        #pragma unroll
        for (int i = 0; i < 4; ++i)
            s_u[i][e] = lng[e] * (uacc[i] - s_S1[i]) + lnb[e] * s_sk[i];
    }
    __syncthreads();
    if (t < E_) {
        const int h = t >> 4;
        float acc = 0.f;
        #pragma unroll
        for (int e = 0; e < E_; ++e) acc += wv[t * E_ + e] * s_u[h][e];
        s_ktv[t] = acc / s_sk[h] + bv[t];
    }
    __syncthreads();
    if (t < E_) {
        #pragma unroll
        for (int h = 0; h < H_; ++h) {
            float acc = 0.f;
            #pragma unroll
            for (int d = 0; d < 16; ++d) acc += wo[t * E_ + h * 16 + d] * s_ktv[h * 16 + d];
            s_wok[t][h] = acc;
        }
    }
    __syncthreads();

    #pragma unroll
    for (int it = 0; it < 2; ++it) {
        const int c = it * 256 + t;
        const float* xp = xbase + c;
        float qn[H_];
        #pragma unroll
        for (int h = 0; h < H_; ++h) qn[h] = qs[it][h] / s_qm[h];
        float* hp = hout + ((size_t)(b * C_ + c) * R_ + r) * E_;
        #pragma unroll
        for (int e4 = 0; e4 < 16; ++e4) {
            float4 o;
            float* ov = (float*)&o;
            #pragma unroll
            for (int i = 0; i < 4; ++i) {
                const int e = e4 * 4 + i;
                float tt = bo[e];
                #pragma unroll
                for (int h = 0; h < H_; ++h) tt += qn[h] * s_wok[e][h];
                ov[i] = xp[(size_t)e * RC] + tt;
            }
            *reinterpret_cast<float4*>(hp + e4 * 4) = o;
        }
    }
}

// ---------------------------------------------------------------------------
// Kernel B: col attention over r (R=1225) for each (b, c). In-place, 5 tiles.
// ---------------------------------------------------------------------------
__global__ __launch_bounds__(256, 4) void col_attn(
    float* __restrict__ hbuf,
    const float* __restrict__ wq, const float* __restrict__ bq,
    const float* __restrict__ wk, const float* __restrict__ bk,
    const float* __restrict__ wv, const float* __restrict__ bv,
    const float* __restrict__ wo, const float* __restrict__ bo,
    const float* __restrict__ lng, const float* __restrict__ lnb)
{
    const int c = blockIdx.x;
    const int b = blockIdx.y;
    const int t = threadIdx.x;
    const int w = t >> 6;
    const int l = t & 63;
    const int lr = l & 15;
    const int lq = l >> 4;

    __shared__ short s_xT[E_][SX];
    __shared__ short s_kb[4][SX];
    __shared__ float s_u[H_][E_];
    __shared__ float s_ktv[E_];
    __shared__ float s_wok[E_][H_];
    __shared__ float s_qm[H_];
    __shared__ float s_sk[H_];
    __shared__ float s_S1[H_];
    __shared__ float red_q[4][H_];
    __shared__ float red_k[4][H_];
    __shared__ float red_k2[4][H_];
    __shared__ float s_cst[16];

    if (t < 16) {
        const int h = t & 3;
        const int kind = t >> 2;
        const float* wm = (kind < 2) ? wq : wk;
        const float* vm = (kind & 1) ? lnb : lng;
        float acc = 0.f;
        for (int e = 0; e < E_; ++e) acc += wm[h * E_ + e] * vm[e];
        s_cst[t] = acc;
    }
    __syncthreads();

    float* hp0 = hbuf + (size_t)(b * C_ + c) * R_ * E_;

    float aq[H_]  = {0.f, 0.f, 0.f, 0.f};
    float ak[H_]  = {0.f, 0.f, 0.f, 0.f};
    float ak2[H_] = {0.f, 0.f, 0.f, 0.f};
    unsigned qs_pk[5][2];
    f32x4 uacc; uacc[0] = uacc[1] = uacc[2] = uacc[3] = 0.f;

    #pragma unroll
    for (int it = 0; it < 5; ++it) {
        const int rr = it * 256 + t;
        if (rr < R_) {
            const float4* pp4 = (const float4*)(hp0 + (size_t)rr * E_);
            float s = 0.f, ss = 0.f;
            float dq[H_] = {0.f, 0.f, 0.f, 0.f};
            float dk[H_] = {0.f, 0.f, 0.f, 0.f};
            #pragma unroll
            for (int e4 = 0; e4 < 16; ++e4) {
                const float4 v4 = pp4[e4];
                const float* vv = (const float*)&v4;
                #pragma unroll
                for (int i = 0; i < 4; ++i) {
                    const int e = e4 * 4 + i;
                    const float xv = vv[i];
                    s += xv; ss += xv * xv;
                    const float t1 = lng[e] * xv;
                    #pragma unroll
                    for (int h = 0; h < H_; ++h) { dq[h] += wq[h * E_ + e] * t1; dk[h] += wk[h * E_ + e] * t1; }
                    s_xT[e][t] = (short)f2bf(xv);
                }
            }
            const float mu = s * (1.f / E_);
            const float rstd = rsqrtf(ss * (1.f / E_) - mu * mu + EPS);
            const float mr = mu * rstd;
            float qv[H_];
            #pragma unroll
            for (int h = 0; h < H_; ++h) {
                qv[h] = elu1(rstd * dq[h] - mr * s_cst[h]     + s_cst[4 + h]  + bq[h]);
                const float kv = elu1(rstd * dk[h] - mr * s_cst[8 + h] + s_cst[12 + h] + bk[h]);
                aq[h] += qv[h]; ak[h] += kv; ak2[h] += kv * mr;
                s_kb[h][t] = (short)f2bf(kv * rstd);
            }
            qs_pk[it][0] = ((unsigned)f2bf(qv[1]) << 16) | f2bf(qv[0]);
            qs_pk[it][1] = ((unsigned)f2bf(qv[3]) << 16) | f2bf(qv[2]);
        } else {
            #pragma unroll
            for (int e = 0; e < E_; ++e) s_xT[e][t] = 0;
            #pragma unroll
            for (int h = 0; h < H_; ++h) s_kb[h][t] = 0;
            qs_pk[it][0] = 0; qs_pk[it][1] = 0;
        }
        __syncthreads();
        #pragma unroll
        for (int ks = 0; ks < 8; ++ks) {
            bf16x8 af;
            #pragma unroll
            for (int i = 0; i < 8; ++i) af[i] = 0;
            if (lr < 4) af = *reinterpret_cast<const bf16x8*>(&s_kb[lr][ks * 32 + lq * 8]);
            const bf16x8 bf = *reinterpret_cast<const bf16x8*>(&s_xT[w * 16 + lr][ks * 32 + lq * 8]);
            uacc = __builtin_amdgcn_mfma_f32_16x16x32_bf16(af, bf, uacc, 0, 0, 0);
        }
        __syncthreads();
    }

    #pragma unroll
    for (int h = 0; h < H_; ++h) {
        #pragma unroll
        for (int off = 32; off; off >>= 1) {
            aq[h] += __shfl_xor(aq[h], off, 64);
            ak[h] += __shfl_xor(ak[h], off, 64);
            ak2[h] += __shfl_xor(ak2[h], off, 64);
        }
    }
    if (l == 0) {
        #pragma unroll
        for (int h = 0; h < H_; ++h) { red_q[w][h] = aq[h]; red_k[w][h] = ak[h]; red_k2[w][h] = ak2[h]; }
    }
    __syncthreads();
    if (t < H_) {
        float sq = 0.f, sk = 0.f, s1 = 0.f;
        #pragma unroll
        for (int w2 = 0; w2 < 4; ++w2) { sq += red_q[w2][t]; sk += red_k[w2][t]; s1 += red_k2[w2][t]; }
        s_qm[t] = sq * (1.f / R_);
        s_sk[t] = sk;
        s_S1[t] = s1;
    }
    __syncthreads();
    if (lq == 0) {
        const int e = w * 16 + lr;
        #pragma unroll
        for (int i = 0; i < 4; ++i)
            s_u[i][e] = lng[e] * (uacc[i] - s_S1[i]) + lnb[e] * s_sk[i];
    }
    __syncthreads();
    if (t < E_) {
        const int h = t >> 4;
        float acc = 0.f;
        #pragma unroll
        for (int e = 0; e < E_; ++e) acc += wv[t * E_ + e] * s_u[h][e];
        s_ktv[t] = acc / s_sk[h] + bv[t];
    }
    __syncthreads();
    if (t < E_) {
        #pragma unroll
        for (int h = 0; h < H_; ++h) {
            float acc = 0.f;
            #pragma unroll
            for (int d = 0; d < 16; ++d) acc += wo[t * E_ + h * 16 + d] * s_ktv[h * 16 + d];
            s_wok[t][h] = acc;
        }
    }
    __syncthreads();

    #pragma unroll
    for (int it = 0; it < 5; ++it) {
        const int rr = it * 256 + t;
        if (rr >= R_) continue;
        float qn[H_];
        qn[0] = bf2f((unsigned short)(qs_pk[it][0] & 0xFFFF)) / s_qm[0];
        qn[1] = bf2f((unsigned short)(qs_pk[it][0] >> 16))    / s_qm[1];
        qn[2] = bf2f((unsigned short)(qs_pk[it][1] & 0xFFFF)) / s_qm[2];
        qn[3] = bf2f((unsigned short)(qs_pk[it][1] >> 16))    / s_qm[3];
        float* pp = hp0 + (size_t)rr * E_;
        #pragma unroll
        for (int e4 = 0; e4 < 16; ++e4) {
            const float4 v4 = *reinterpret_cast<const float4*>(pp + e4 * 4);
            const float* hv4 = (const float*)&v4;
            float4 o;
            float* ov = (float*)&o;
            #pragma unroll
            for (int i = 0; i < 4; ++i) {
                const int e = e4 * 4 + i;
                float tt = bo[e];
                #pragma unroll
                for (int h = 0; h < H_; ++h) tt += qn[h] * s_wok[e][h];
                ov[i] = hv4[i] + tt;
            }
            *reinterpret_cast<float4*>(pp + e4 * 4) = o;
        }
    }
}

// ---------------------------------------------------------------------------
// prep_weights: fp32 -> bf16 for w1/w2.
// ---------------------------------------------------------------------------
__global__ __launch_bounds__(256) void prep_weights(
    const float* __restrict__ w1, const float* __restrict__ w2,
    short* __restrict__ w1b, short* __restrict__ w2b)
{
    const int i = blockIdx.x * 256 + threadIdx.x;
    if (i < 16384) w1b[i] = (short)f2bf(w1[i]);
    else           w2b[i - 16384] = (short)f2bf(w2[i - 16384]);
}

// ---------------------------------------------------------------------------
// Kernel C: MFMA bf16 FFN (unchanged from round 4).
// ---------------------------------------------------------------------------
#define SA 72
#define SG 264
#define SO 65

template <bool PREP>
__global__ __launch_bounds__(256) void ffn_mfma(
    const float* __restrict__ hbuf,
    const float* __restrict__ lng, const float* __restrict__ lnb,
    const float* __restrict__ w1, const short* __restrict__ w1b,
    const float* __restrict__ b1,
    const float* __restrict__ w2, const short* __restrict__ w2b,
    const float* __restrict__ b2,
    float* __restrict__ out)
{
    __shared__ __align__(16) char smem[33792 + 16640];
    short* s_g = (short*)smem;
    short* s_a = (short*)(smem + 33792);
    float* s_o = (float*)(smem + 33792);

    const int t = threadIdx.x;
    const int w = t >> 6;
    const int l = t & 63;
    const int lr = l & 15;
    const int lq = l >> 4;

    const int bid = blockIdx.x;
    const int cb  = bid & 7;
    const int rem = bid >> 3;
    const int r   = rem % R_;
    const int b   = rem / R_;
    const int c0  = cb * 64;

    {
        const int m  = t >> 2;
        const int qi = t & 3;
        const float* hp = hbuf + ((size_t)(b * C_ + c0 + m) * R_ + r) * E_ + qi * 16;
        const float4* hp4 = (const float4*)hp;
        float4 v0 = hp4[0], v1 = hp4[1], v2 = hp4[2], v3 = hp4[3];
        float hv[16];
        hv[0]=v0.x; hv[1]=v0.y; hv[2]=v0.z; hv[3]=v0.w;
        hv[4]=v1.x; hv[5]=v1.y; hv[6]=v1.z; hv[7]=v1.w;
        hv[8]=v2.x; hv[9]=v2.y; hv[10]=v2.z; hv[11]=v2.w;
        hv[12]=v3.x; hv[13]=v3.y; hv[14]=v3.z; hv[15]=v3.w;
        float s = 0.f, ss = 0.f;
        #pragma unroll
        for (int i = 0; i < 16; ++i) { s += hv[i]; ss += hv[i] * hv[i]; }
        s  += __shfl_xor(s, 1, 64);  s  += __shfl_xor(s, 2, 64);
        ss += __shfl_xor(ss, 1, 64); ss += __shfl_xor(ss, 2, 64);
        const float mu = s * (1.f / 64.f);
        const float rstd = rsqrtf(ss * (1.f / 64.f) - mu * mu + EPS);
        bf16x8 o0, o1;
        #pragma unroll
        for (int i = 0; i < 8; ++i) {
            const int e = qi * 16 + i;
            o0[i] = (short)f2bf((hv[i] - mu) * rstd * lng[e] + lnb[e]);
        }
        #pragma unroll
        for (int i = 0; i < 8; ++i) {
            const int e = qi * 16 + 8 + i;
            o1[i] = (short)f2bf((hv[8 + i] - mu) * rstd * lng[e] + lnb[e]);
        }
        *reinterpret_cast<bf16x8*>(&s_a[m * SA + qi * 16])     = o0;
        *reinterpret_cast<bf16x8*>(&s_a[m * SA + qi * 16 + 8]) = o1;
    }
    __syncthreads();

    {
        bf16x8 bfr[4][2];
        #pragma unroll
        for (int mt = 0; mt < 4; ++mt)
            #pragma unroll
            for (int ks = 0; ks < 2; ++ks)
                bfr[mt][ks] = *reinterpret_cast<const bf16x8*>(
                    &s_a[(mt * 16 + lr) * SA + ks * 32 + lq * 8]);

        #pragma unroll
        for (int nn = 0; nn < 4; ++nn) {
            const int jt = w * 4 + nn;
            bf16x8 afr[2];
            if (PREP) {
                #pragma unroll
                for (int ks = 0; ks < 2; ++ks)
                    afr[ks] = *reinterpret_cast<const bf16x8*>(
                        w1b + (size_t)(jt * 16 + lr) * 64 + ks * 32 + lq * 8);
            } else {
                #pragma unroll
                for (int ks = 0; ks < 2; ++ks) {
                    const float4* wp = (const float4*)(w1 + (size_t)(jt * 16 + lr) * 64 + ks * 32 + lq * 8);
                    afr[ks] = pack8(wp[0], wp[1]);
                }
            }
            f32x4 acc[4];
            #pragma unroll
            for (int mt = 0; mt < 4; ++mt) { acc[mt][0]=0.f; acc[mt][1]=0.f; acc[mt][2]=0.f; acc[mt][3]=0.f; }
            #pragma unroll
            for (int ks = 0; ks < 2; ++ks)
                #pragma unroll
                for (int mt = 0; mt < 4; ++mt)
                    acc[mt] = __builtin_amdgcn_mfma_f32_16x16x32_bf16(afr[ks], bfr[mt][ks], acc[mt], 0, 0, 0);

            const float4 b1v = *reinterpret_cast<const float4*>(&b1[jt * 16 + lq * 4]);
            const float* b1p = (const float*)&b1v;
            #pragma unroll
            for (int mt = 0; mt < 4; ++mt) {
                const int m = mt * 16 + lr;
                bf16x4 pk;
                #pragma unroll
                for (int i = 0; i < 4; ++i) {
                    const float aa = acc[mt][i] + b1p[i];
                    pk[i] = (short)f2bf(gelu_fast(aa));
                }
                *reinterpret_cast<bf16x4*>(&s_g[m * SG + jt * 16 + lq * 4]) = pk;
            }
        }
    }
    __syncthreads();

    {
        f32x4 acc2[4];
        #pragma unroll
        for (int mt = 0; mt < 4; ++mt) { acc2[mt][0]=0.f; acc2[mt][1]=0.f; acc2[mt][2]=0.f; acc2[mt][3]=0.f; }
        const int n = w * 16 + lr;
        #pragma unroll
        for (int ks = 0; ks < 8; ++ks) {
            bf16x8 bfr;
            if (PREP) {
                bfr = *reinterpret_cast<const bf16x8*>(w2b + (size_t)n * 256 + ks * 32 + lq * 8);
            } else {
                const float4* wp = (const float4*)(w2 + (size_t)n * 256 + ks * 32 + lq * 8);
                bfr = pack8(wp[0], wp[1]);
            }
            #pragma unroll
            for (int mt = 0; mt < 4; ++mt) {
                const bf16x8 af = *reinterpret_cast<const bf16x8*>(
                    &s_g[(mt * 16 + lr) * SG + ks * 32 + lq * 8]);
                acc2[mt] = __builtin_amdgcn_mfma_f32_16x16x32_bf16(af, bfr, acc2[mt], 0, 0, 0);
            }
        }
        #pragma unroll
        for (int mt = 0; mt < 4; ++mt)
            #pragma unroll
            for (int i = 0; i < 4; ++i)
                s_o[(mt * 16 + lq * 4 + i) * SO + n] = acc2[mt][i];
    }
    __syncthreads();

    {
        const int m  = t & 63;
        const int eb = (t >> 6) * 16;
        const int c  = c0 + m;
        const float* hp = hbuf + ((size_t)(b * C_ + c) * R_ + r) * E_ + eb;
        const float4* hp4 = (const float4*)hp;
        float4 v0 = hp4[0], v1 = hp4[1], v2 = hp4[2], v3 = hp4[3];
        float hv[16];
        hv[0]=v0.x; hv[1]=v0.y; hv[2]=v0.z; hv[3]=v0.w;
        hv[4]=v1.x; hv[5]=v1.y; hv[6]=v1.z; hv[7]=v1.w;
        hv[8]=v2.x; hv[9]=v2.y; hv[10]=v2.z; hv[11]=v2.w;
        hv[12]=v3.x; hv[13]=v3.y; hv[14]=v3.z; hv[15]=v3.w;
        #pragma unroll
        for (int i = 0; i < 16; ++i) {
            const int e = eb + i;
            const float val = s_o[m * SO + e] + b2[e] + hv[i];
            out[(((size_t)b * E_ + e) * R_ + r) * C_ + c] = val;
        }
    }
}

extern "C" void kernel_launch(void* const* d_in, const int* in_sizes, int n_in,
                              void* d_out, int out_size, void* d_ws, size_t ws_size,
                              hipStream_t stream) {
    const float* x      = (const float*)d_in[0];
    const float* row_wq = (const float*)d_in[1];
    const float* row_bq = (const float*)d_in[2];
    const float* row_wk = (const float*)d_in[3];
    const float* row_bk = (const float*)d_in[4];
    const float* row_wv = (const float*)d_in[5];
    const float* row_bv = (const float*)d_in[6];
    const float* row_wo = (const float*)d_in[7];
    const float* row_bo = (const float*)d_in[8];
    const float* col_wq = (const float*)d_in[9];
    const float* col_bq = (const float*)d_in[10];
    const float* col_wk = (const float*)d_in[11];
    const float* col_bk = (const float*)d_in[12];
    const float* col_wv = (const float*)d_in[13];
    const float* col_bv = (const float*)d_in[14];
    const float* col_wo = (const float*)d_in[15];
    const float* col_bo = (const float*)d_in[16];
    const float* rn_g   = (const float*)d_in[17];
    const float* rn_b   = (const float*)d_in[18];
    const float* cn_g   = (const float*)d_in[19];
    const float* cn_b   = (const float*)d_in[20];
    const float* fn_g   = (const float*)d_in[21];
    const float* fn_b   = (const float*)d_in[22];
    const float* w1     = (const float*)d_in[23];
    const float* b1     = (const float*)d_in[24];
    const float* w2     = (const float*)d_in[25];
    const float* b2     = (const float*)d_in[26];

    const size_t need = (size_t)B_ * C_ * R_ * E_ * sizeof(float);
    if (ws_size < need) return;
    float* hbuf = (float*)d_ws;

    const bool prep = (ws_size >= need + 2 * 16384 * sizeof(short) + 256);
    short* w1b = (short*)((char*)d_ws + need);
    short* w2b = w1b + 16384;

    row_attn<<<dim3(R_, B_), 256, 0, stream>>>(
        x, row_wq, row_bq, row_wk, row_bk, row_wv, row_bv, row_wo, row_bo,
        rn_g, rn_b, hbuf);
    col_attn<<<dim3(C_, B_), 256, 0, stream>>>(
        hbuf, col_wq, col_bq, col_wk, col_bk, col_wv, col_bv, col_wo, col_bo,
        cn_g, cn_b);
    if (prep) {
        prep_weights<<<128, 256, 0, stream>>>(w1, w2, w1b, w2b);
        ffn_mfma<true><<<B_ * R_ * 8, 256, 0, stream>>>(
            hbuf, fn_g, fn_b, w1, w1b, b1, w2, w2b, b2, (float*)d_out);
    } else {
        ffn_mfma<false><<<B_ * R_ * 8, 256, 0, stream>>>(
            hbuf, fn_g, fn_b, w1, w1b, b1, w2, w2b, b2, (float*)d_out);
    }
}

// Round 7
// 1382.318 us; speedup vs baseline: 1.2593x; 1.0167x over previous
//
#include <hip/hip_runtime.h>
#include <cmath>

#define E_ 64
#define H_ 4
#define B_ 2
#define R_ 1225
#define C_ 512
#define EPS 1e-5f

__device__ __forceinline__ float elu1(float a) { return a > 0.f ? a + 1.f : __expf(a); }

typedef float f32x4 __attribute__((ext_vector_type(4)));
typedef short bf16x8 __attribute__((ext_vector_type(8)));
typedef short bf16x4 __attribute__((ext_vector_type(4)));

__device__ __forceinline__ unsigned short f2bf(float f) {
    union { float f; unsigned u; } c; c.f = f;
    unsigned u = c.u + 0x7FFFu + ((c.u >> 16) & 1u);   // RNE
    return (unsigned short)(u >> 16);
}

__device__ __forceinline__ float bf2f(unsigned short s) {
    union { unsigned u; float f; } c; c.u = ((unsigned)s) << 16;
    return c.f;
}

__device__ __forceinline__ bf16x8 pack8(float4 a, float4 b) {
    bf16x8 r;
    r[0] = (short)f2bf(a.x); r[1] = (short)f2bf(a.y);
    r[2] = (short)f2bf(a.z); r[3] = (short)f2bf(a.w);
    r[4] = (short)f2bf(b.x); r[5] = (short)f2bf(b.y);
    r[6] = (short)f2bf(b.z); r[7] = (short)f2bf(b.w);
    return r;
}

// tanh-approx GELU in sigmoid form (max dev ~3e-4 vs exact-erf)
__device__ __forceinline__ float gelu_fast(float a) {
    const float u = a * (-1.5957691216057308f - 0.0713548162726009f * a * a);
    return a / (1.f + __expf(u));
}

#define SX 264   // LDS row stride (256+8) in bf16

// ---------------------------------------------------------------------------
// Attention math: LN is per-position affine =>
//   q_pre[h] = rstd*dq[h] - rstd*mu*WgQ[h] + CQ[h] + bq[h],  dq = sum wq*g*xv
//   u[h][e]  = g[e]*(M1[h][e] - S1[h]) + lb[e]*sk[h]
//   M1[h][e] = sum_c (k_c*rstd_c) * xv[c,e]   (MFMA on RAW x)
// => no 64-float arrays in registers.
// launch_bounds(256,3): VGPR cap ~170 (the (256,4) cap made the unified-RF
// split 64 arch VGPRs -> spill, r5/r6). Occupancy stays LDS-bound (4 blk/CU).
// ---------------------------------------------------------------------------

// ---------------------------------------------------------------------------
// Kernel A: row attention over c (C=512) for each (b, r). 256 thr, 2 tiles.
// ---------------------------------------------------------------------------
__global__ __launch_bounds__(256, 3) void row_attn(
    const float* __restrict__ x,
    const float* __restrict__ wq, const float* __restrict__ bq,
    const float* __restrict__ wk, const float* __restrict__ bk,
    const float* __restrict__ wv, const float* __restrict__ bv,
    const float* __restrict__ wo, const float* __restrict__ bo,
    const float* __restrict__ lng, const float* __restrict__ lnb,
    float* __restrict__ hout)
{
    const int r = blockIdx.x;
    const int b = blockIdx.y;
    const int t = threadIdx.x;
    const int w = t >> 6;
    const int l = t & 63;
    const int lr = l & 15;
    const int lq = l >> 4;

    __shared__ short s_xT[E_][SX];     // raw x, bf16, [e][pos-in-tile]
    __shared__ short s_kb[4][SX];      // k*rstd, bf16
    __shared__ float s_u[H_][E_];
    __shared__ float s_ktv[E_];
    __shared__ float s_wok[E_][H_];
    __shared__ float s_qm[H_];
    __shared__ float s_sk[H_];
    __shared__ float s_S1[H_];
    __shared__ float red_q[4][H_];
    __shared__ float red_k[4][H_];
    __shared__ float red_k2[4][H_];
    __shared__ float s_cst[16];        // WgQ[4] CQ[4] WgK[4] CK[4]

    // block-uniform constants
    if (t < 16) {
        const int h = t & 3;
        const int kind = t >> 2;                    // 0 WgQ, 1 CQ, 2 WgK, 3 CK
        const float* wm = (kind < 2) ? wq : wk;
        const float* vm = (kind & 1) ? lnb : lng;
        float acc = 0.f;
        for (int e = 0; e < E_; ++e) acc += wm[h * E_ + e] * vm[e];
        s_cst[t] = acc;
    }
    __syncthreads();

    const size_t RC = (size_t)R_ * C_;
    const float* xbase = x + (size_t)b * E_ * RC + (size_t)r * C_;

    float aq[H_]  = {0.f, 0.f, 0.f, 0.f};
    float ak[H_]  = {0.f, 0.f, 0.f, 0.f};
    float ak2[H_] = {0.f, 0.f, 0.f, 0.f};
    float qs[2][H_];
    f32x4 uacc; uacc[0] = uacc[1] = uacc[2] = uacc[3] = 0.f;

    #pragma unroll
    for (int it = 0; it < 2; ++it) {
        const float* xp = xbase + it * 256 + t;
        float s = 0.f, ss = 0.f;
        float dq[H_] = {0.f, 0.f, 0.f, 0.f};
        float dk[H_] = {0.f, 0.f, 0.f, 0.f};
        // unroll 16: caps in-flight strided loads (register demand) at ~16
        #pragma unroll 16
        for (int e = 0; e < E_; ++e) {
            const float xv = xp[(size_t)e * RC];
            s += xv; ss += xv * xv;
            const float t1 = lng[e] * xv;
            #pragma unroll
            for (int h = 0; h < H_; ++h) { dq[h] += wq[h * E_ + e] * t1; dk[h] += wk[h * E_ + e] * t1; }
            s_xT[e][t] = (short)f2bf(xv);
        }
        const float mu = s * (1.f / E_);
        const float rstd = rsqrtf(ss * (1.f / E_) - mu * mu + EPS);
        const float mr = mu * rstd;
        #pragma unroll
        for (int h = 0; h < H_; ++h) {
            const float qv = elu1(rstd * dq[h] - mr * s_cst[h]     + s_cst[4 + h]  + bq[h]);
            const float kv = elu1(rstd * dk[h] - mr * s_cst[8 + h] + s_cst[12 + h] + bk[h]);
            qs[it][h] = qv;
            aq[h] += qv; ak[h] += kv; ak2[h] += kv * mr;
            s_kb[h][t] = (short)f2bf(kv * rstd);
        }
        __syncthreads();
        #pragma unroll
        for (int ks = 0; ks < 8; ++ks) {
            bf16x8 af;
            #pragma unroll
            for (int i = 0; i < 8; ++i) af[i] = 0;
            if (lr < 4) af = *reinterpret_cast<const bf16x8*>(&s_kb[lr][ks * 32 + lq * 8]);
            const bf16x8 bf = *reinterpret_cast<const bf16x8*>(&s_xT[w * 16 + lr][ks * 32 + lq * 8]);
            uacc = __builtin_amdgcn_mfma_f32_16x16x32_bf16(af, bf, uacc, 0, 0, 0);
        }
        __syncthreads();
    }

    // reductions of sum_q, sum_k, sum k*rstd*mu
    #pragma unroll
    for (int h = 0; h < H_; ++h) {
        #pragma unroll
        for (int off = 32; off; off >>= 1) {
            aq[h] += __shfl_xor(aq[h], off, 64);
            ak[h] += __shfl_xor(ak[h], off, 64);
            ak2[h] += __shfl_xor(ak2[h], off, 64);
        }
    }
    if (l == 0) {
        #pragma unroll
        for (int h = 0; h < H_; ++h) { red_q[w][h] = aq[h]; red_k[w][h] = ak[h]; red_k2[w][h] = ak2[h]; }
    }
    __syncthreads();
    if (t < H_) {
        float sq = 0.f, sk = 0.f, s1 = 0.f;
        #pragma unroll
        for (int w2 = 0; w2 < 4; ++w2) { sq += red_q[w2][t]; sk += red_k[w2][t]; s1 += red_k2[w2][t]; }
        s_qm[t] = sq * (1.f / C_);
        s_sk[t] = sk;
        s_S1[t] = s1;
    }
    __syncthreads();
    // corrected u: u[h][e] = g[e]*(M1 - S1[h]) + lb[e]*sk[h]
    if (lq == 0) {
        const int e = w * 16 + lr;
        #pragma unroll
        for (int i = 0; i < 4; ++i)
            s_u[i][e] = lng[e] * (uacc[i] - s_S1[i]) + lnb[e] * s_sk[i];
    }
    __syncthreads();
    if (t < E_) {
        const int h = t >> 4;
        float acc = 0.f;
        #pragma unroll
        for (int e = 0; e < E_; ++e) acc += wv[t * E_ + e] * s_u[h][e];
        s_ktv[t] = acc / s_sk[h] + bv[t];
    }
    __syncthreads();
    if (t < E_) {
        #pragma unroll
        for (int h = 0; h < H_; ++h) {
            float acc = 0.f;
            #pragma unroll
            for (int d = 0; d < 16; ++d) acc += wo[t * E_ + h * 16 + d] * s_ktv[h * 16 + d];
            s_wok[t][h] = acc;
        }
    }
    __syncthreads();

    #pragma unroll
    for (int it = 0; it < 2; ++it) {
        const int c = it * 256 + t;
        const float* xp = xbase + c;
        float qn[H_];
        #pragma unroll
        for (int h = 0; h < H_; ++h) qn[h] = qs[it][h] / s_qm[h];
        float* hp = hout + ((size_t)(b * C_ + c) * R_ + r) * E_;
        #pragma unroll 4
        for (int e4 = 0; e4 < 16; ++e4) {
            float4 o;
            float* ov = (float*)&o;
            #pragma unroll
            for (int i = 0; i < 4; ++i) {
                const int e = e4 * 4 + i;
                float tt = bo[e];
                #pragma unroll
                for (int h = 0; h < H_; ++h) tt += qn[h] * s_wok[e][h];
                ov[i] = xp[(size_t)e * RC] + tt;
            }
            *reinterpret_cast<float4*>(hp + e4 * 4) = o;
        }
    }
}

// ---------------------------------------------------------------------------
// Kernel B: col attention over r (R=1225) for each (b, c). In-place, 5 tiles.
// ---------------------------------------------------------------------------
__global__ __launch_bounds__(256, 3) void col_attn(
    float* __restrict__ hbuf,
    const float* __restrict__ wq, const float* __restrict__ bq,
    const float* __restrict__ wk, const float* __restrict__ bk,
    const float* __restrict__ wv, const float* __restrict__ bv,
    const float* __restrict__ wo, const float* __restrict__ bo,
    const float* __restrict__ lng, const float* __restrict__ lnb)
{
    const int c = blockIdx.x;
    const int b = blockIdx.y;
    const int t = threadIdx.x;
    const int w = t >> 6;
    const int l = t & 63;
    const int lr = l & 15;
    const int lq = l >> 4;

    __shared__ short s_xT[E_][SX];
    __shared__ short s_kb[4][SX];
    __shared__ float s_u[H_][E_];
    __shared__ float s_ktv[E_];
    __shared__ float s_wok[E_][H_];
    __shared__ float s_qm[H_];
    __shared__ float s_sk[H_];
    __shared__ float s_S1[H_];
    __shared__ float red_q[4][H_];
    __shared__ float red_k[4][H_];
    __shared__ float red_k2[4][H_];
    __shared__ float s_cst[16];

    if (t < 16) {
        const int h = t & 3;
        const int kind = t >> 2;
        const float* wm = (kind < 2) ? wq : wk;
        const float* vm = (kind & 1) ? lnb : lng;
        float acc = 0.f;
        for (int e = 0; e < E_; ++e) acc += wm[h * E_ + e] * vm[e];
        s_cst[t] = acc;
    }
    __syncthreads();

    float* hp0 = hbuf + (size_t)(b * C_ + c) * R_ * E_;

    float aq[H_]  = {0.f, 0.f, 0.f, 0.f};
    float ak[H_]  = {0.f, 0.f, 0.f, 0.f};
    float ak2[H_] = {0.f, 0.f, 0.f, 0.f};
    unsigned qs_pk[5][2];
    f32x4 uacc; uacc[0] = uacc[1] = uacc[2] = uacc[3] = 0.f;

    #pragma unroll
    for (int it = 0; it < 5; ++it) {
        const int rr = it * 256 + t;
        if (rr < R_) {
            const float4* pp4 = (const float4*)(hp0 + (size_t)rr * E_);
            float s = 0.f, ss = 0.f;
            float dq[H_] = {0.f, 0.f, 0.f, 0.f};
            float dk[H_] = {0.f, 0.f, 0.f, 0.f};
            // unroll 4: caps in-flight float4 loads at 4 (16 regs)
            #pragma unroll 4
            for (int e4 = 0; e4 < 16; ++e4) {
                const float4 v4 = pp4[e4];
                const float* vv = (const float*)&v4;
                #pragma unroll
                for (int i = 0; i < 4; ++i) {
                    const int e = e4 * 4 + i;
                    const float xv = vv[i];
                    s += xv; ss += xv * xv;
                    const float t1 = lng[e] * xv;
                    #pragma unroll
                    for (int h = 0; h < H_; ++h) { dq[h] += wq[h * E_ + e] * t1; dk[h] += wk[h * E_ + e] * t1; }
                    s_xT[e][t] = (short)f2bf(xv);
                }
            }
            const float mu = s * (1.f / E_);
            const float rstd = rsqrtf(ss * (1.f / E_) - mu * mu + EPS);
            const float mr = mu * rstd;
            float qv[H_];
            #pragma unroll
            for (int h = 0; h < H_; ++h) {
                qv[h] = elu1(rstd * dq[h] - mr * s_cst[h]     + s_cst[4 + h]  + bq[h]);
                const float kv = elu1(rstd * dk[h] - mr * s_cst[8 + h] + s_cst[12 + h] + bk[h]);
                aq[h] += qv[h]; ak[h] += kv; ak2[h] += kv * mr;
                s_kb[h][t] = (short)f2bf(kv * rstd);
            }
            qs_pk[it][0] = ((unsigned)f2bf(qv[1]) << 16) | f2bf(qv[0]);
            qs_pk[it][1] = ((unsigned)f2bf(qv[3]) << 16) | f2bf(qv[2]);
        } else {
            #pragma unroll
            for (int e = 0; e < E_; ++e) s_xT[e][t] = 0;
            #pragma unroll
            for (int h = 0; h < H_; ++h) s_kb[h][t] = 0;
            qs_pk[it][0] = 0; qs_pk[it][1] = 0;
        }
        __syncthreads();
        #pragma unroll
        for (int ks = 0; ks < 8; ++ks) {
            bf16x8 af;
            #pragma unroll
            for (int i = 0; i < 8; ++i) af[i] = 0;
            if (lr < 4) af = *reinterpret_cast<const bf16x8*>(&s_kb[lr][ks * 32 + lq * 8]);
            const bf16x8 bf = *reinterpret_cast<const bf16x8*>(&s_xT[w * 16 + lr][ks * 32 + lq * 8]);
            uacc = __builtin_amdgcn_mfma_f32_16x16x32_bf16(af, bf, uacc, 0, 0, 0);
        }
        __syncthreads();
    }

    #pragma unroll
    for (int h = 0; h < H_; ++h) {
        #pragma unroll
        for (int off = 32; off; off >>= 1) {
            aq[h] += __shfl_xor(aq[h], off, 64);
            ak[h] += __shfl_xor(ak[h], off, 64);
            ak2[h] += __shfl_xor(ak2[h], off, 64);
        }
    }
    if (l == 0) {
        #pragma unroll
        for (int h = 0; h < H_; ++h) { red_q[w][h] = aq[h]; red_k[w][h] = ak[h]; red_k2[w][h] = ak2[h]; }
    }
    __syncthreads();
    if (t < H_) {
        float sq = 0.f, sk = 0.f, s1 = 0.f;
        #pragma unroll
        for (int w2 = 0; w2 < 4; ++w2) { sq += red_q[w2][t]; sk += red_k[w2][t]; s1 += red_k2[w2][t]; }
        s_qm[t] = sq * (1.f / R_);
        s_sk[t] = sk;
        s_S1[t] = s1;
    }
    __syncthreads();
    if (lq == 0) {
        const int e = w * 16 + lr;
        #pragma unroll
        for (int i = 0; i < 4; ++i)
            s_u[i][e] = lng[e] * (uacc[i] - s_S1[i]) + lnb[e] * s_sk[i];
    }
    __syncthreads();
    if (t < E_) {
        const int h = t >> 4;
        float acc = 0.f;
        #pragma unroll
        for (int e = 0; e < E_; ++e) acc += wv[t * E_ + e] * s_u[h][e];
        s_ktv[t] = acc / s_sk[h] + bv[t];
    }
    __syncthreads();
    if (t < E_) {
        #pragma unroll
        for (int h = 0; h < H_; ++h) {
            float acc = 0.f;
            #pragma unroll
            for (int d = 0; d < 16; ++d) acc += wo[t * E_ + h * 16 + d] * s_ktv[h * 16 + d];
            s_wok[t][h] = acc;
        }
    }
    __syncthreads();

    #pragma unroll
    for (int it = 0; it < 5; ++it) {
        const int rr = it * 256 + t;
        if (rr >= R_) continue;
        float qn[H_];
        qn[0] = bf2f((unsigned short)(qs_pk[it][0] & 0xFFFF)) / s_qm[0];
        qn[1] = bf2f((unsigned short)(qs_pk[it][0] >> 16))    / s_qm[1];
        qn[2] = bf2f((unsigned short)(qs_pk[it][1] & 0xFFFF)) / s_qm[2];
        qn[3] = bf2f((unsigned short)(qs_pk[it][1] >> 16))    / s_qm[3];
        float* pp = hp0 + (size_t)rr * E_;
        #pragma unroll 4
        for (int e4 = 0; e4 < 16; ++e4) {
            const float4 v4 = *reinterpret_cast<const float4*>(pp + e4 * 4);
            const float* hv4 = (const float*)&v4;
            float4 o;
            float* ov = (float*)&o;
            #pragma unroll
            for (int i = 0; i < 4; ++i) {
                const int e = e4 * 4 + i;
                float tt = bo[e];
                #pragma unroll
                for (int h = 0; h < H_; ++h) tt += qn[h] * s_wok[e][h];
                ov[i] = hv4[i] + tt;
            }
            *reinterpret_cast<float4*>(pp + e4 * 4) = o;
        }
    }
}

// ---------------------------------------------------------------------------
// prep_weights: fp32 -> bf16 for w1/w2.
// ---------------------------------------------------------------------------
__global__ __launch_bounds__(256) void prep_weights(
    const float* __restrict__ w1, const float* __restrict__ w2,
    short* __restrict__ w1b, short* __restrict__ w2b)
{
    const int i = blockIdx.x * 256 + threadIdx.x;
    if (i < 16384) w1b[i] = (short)f2bf(w1[i]);
    else           w2b[i - 16384] = (short)f2bf(w2[i - 16384]);
}

// ---------------------------------------------------------------------------
// Kernel C: MFMA bf16 FFN (unchanged).
// ---------------------------------------------------------------------------
#define SA 72
#define SG 264
#define SO 65

template <bool PREP>
__global__ __launch_bounds__(256) void ffn_mfma(
    const float* __restrict__ hbuf,
    const float* __restrict__ lng, const float* __restrict__ lnb,
    const float* __restrict__ w1, const short* __restrict__ w1b,
    const float* __restrict__ b1,
    const float* __restrict__ w2, const short* __restrict__ w2b,
    const float* __restrict__ b2,
    float* __restrict__ out)
{
    __shared__ __align__(16) char smem[33792 + 16640];
    short* s_g = (short*)smem;
    short* s_a = (short*)(smem + 33792);
    float* s_o = (float*)(smem + 33792);

    const int t = threadIdx.x;
    const int w = t >> 6;
    const int l = t & 63;
    const int lr = l & 15;
    const int lq = l >> 4;

    const int bid = blockIdx.x;
    const int cb  = bid & 7;
    const int rem = bid >> 3;
    const int r   = rem % R_;
    const int b   = rem / R_;
    const int c0  = cb * 64;

    {
        const int m  = t >> 2;
        const int qi = t & 3;
        const float* hp = hbuf + ((size_t)(b * C_ + c0 + m) * R_ + r) * E_ + qi * 16;
        const float4* hp4 = (const float4*)hp;
        float4 v0 = hp4[0], v1 = hp4[1], v2 = hp4[2], v3 = hp4[3];
        float hv[16];
        hv[0]=v0.x; hv[1]=v0.y; hv[2]=v0.z; hv[3]=v0.w;
        hv[4]=v1.x; hv[5]=v1.y; hv[6]=v1.z; hv[7]=v1.w;
        hv[8]=v2.x; hv[9]=v2.y; hv[10]=v2.z; hv[11]=v2.w;
        hv[12]=v3.x; hv[13]=v3.y; hv[14]=v3.z; hv[15]=v3.w;
        float s = 0.f, ss = 0.f;
        #pragma unroll
        for (int i = 0; i < 16; ++i) { s += hv[i]; ss += hv[i] * hv[i]; }
        s  += __shfl_xor(s, 1, 64);  s  += __shfl_xor(s, 2, 64);
        ss += __shfl_xor(ss, 1, 64); ss += __shfl_xor(ss, 2, 64);
        const float mu = s * (1.f / 64.f);
        const float rstd = rsqrtf(ss * (1.f / 64.f) - mu * mu + EPS);
        bf16x8 o0, o1;
        #pragma unroll
        for (int i = 0; i < 8; ++i) {
            const int e = qi * 16 + i;
            o0[i] = (short)f2bf((hv[i] - mu) * rstd * lng[e] + lnb[e]);
        }
        #pragma unroll
        for (int i = 0; i < 8; ++i) {
            const int e = qi * 16 + 8 + i;
            o1[i] = (short)f2bf((hv[8 + i] - mu) * rstd * lng[e] + lnb[e]);
        }
        *reinterpret_cast<bf16x8*>(&s_a[m * SA + qi * 16])     = o0;
        *reinterpret_cast<bf16x8*>(&s_a[m * SA + qi * 16 + 8]) = o1;
    }
    __syncthreads();

    {
        bf16x8 bfr[4][2];
        #pragma unroll
        for (int mt = 0; mt < 4; ++mt)
            #pragma unroll
            for (int ks = 0; ks < 2; ++ks)
                bfr[mt][ks] = *reinterpret_cast<const bf16x8*>(
                    &s_a[(mt * 16 + lr) * SA + ks * 32 + lq * 8]);

        #pragma unroll
        for (int nn = 0; nn < 4; ++nn) {
            const int jt = w * 4 + nn;
            bf16x8 afr[2];
            if (PREP) {
                #pragma unroll
                for (int ks = 0; ks < 2; ++ks)
                    afr[ks] = *reinterpret_cast<const bf16x8*>(
                        w1b + (size_t)(jt * 16 + lr) * 64 + ks * 32 + lq * 8);
            } else {
                #pragma unroll
                for (int ks = 0; ks < 2; ++ks) {
                    const float4* wp = (const float4*)(w1 + (size_t)(jt * 16 + lr) * 64 + ks * 32 + lq * 8);
                    afr[ks] = pack8(wp[0], wp[1]);
                }
            }
            f32x4 acc[4];
            #pragma unroll
            for (int mt = 0; mt < 4; ++mt) { acc[mt][0]=0.f; acc[mt][1]=0.f; acc[mt][2]=0.f; acc[mt][3]=0.f; }
            #pragma unroll
            for (int ks = 0; ks < 2; ++ks)
                #pragma unroll
                for (int mt = 0; mt < 4; ++mt)
                    acc[mt] = __builtin_amdgcn_mfma_f32_16x16x32_bf16(afr[ks], bfr[mt][ks], acc[mt], 0, 0, 0);

            const float4 b1v = *reinterpret_cast<const float4*>(&b1[jt * 16 + lq * 4]);
            const float* b1p = (const float*)&b1v;
            #pragma unroll
            for (int mt = 0; mt < 4; ++mt) {
                const int m = mt * 16 + lr;
                bf16x4 pk;
                #pragma unroll
                for (int i = 0; i < 4; ++i) {
                    const float aa = acc[mt][i] + b1p[i];
                    pk[i] = (short)f2bf(gelu_fast(aa));
                }
                *reinterpret_cast<bf16x4*>(&s_g[m * SG + jt * 16 + lq * 4]) = pk;
            }
        }
    }
    __syncthreads();

    {
        f32x4 acc2[4];
        #pragma unroll
        for (int mt = 0; mt < 4; ++mt) { acc2[mt][0]=0.f; acc2[mt][1]=0.f; acc2[mt][2]=0.f; acc2[mt][3]=0.f; }
        const int n = w * 16 + lr;
        #pragma unroll
        for (int ks = 0; ks < 8; ++ks) {
            bf16x8 bfr;
            if (PREP) {
                bfr = *reinterpret_cast<const bf16x8*>(w2b + (size_t)n * 256 + ks * 32 + lq * 8);
            } else {
                const float4* wp = (const float4*)(w2 + (size_t)n * 256 + ks * 32 + lq * 8);
                bfr = pack8(wp[0], wp[1]);
            }
            #pragma unroll
            for (int mt = 0; mt < 4; ++mt) {
                const bf16x8 af = *reinterpret_cast<const bf16x8*>(
                    &s_g[(mt * 16 + lr) * SG + ks * 32 + lq * 8]);
                acc2[mt] = __builtin_amdgcn_mfma_f32_16x16x32_bf16(af, bfr, acc2[mt], 0, 0, 0);
            }
        }
        #pragma unroll
        for (int mt = 0; mt < 4; ++mt)
            #pragma unroll
            for (int i = 0; i < 4; ++i)
                s_o[(mt * 16 + lq * 4 + i) * SO + n] = acc2[mt][i];
    }
    __syncthreads();

    {
        const int m  = t & 63;
        const int eb = (t >> 6) * 16;
        const int c  = c0 + m;
        const float* hp = hbuf + ((size_t)(b * C_ + c) * R_ + r) * E_ + eb;
        const float4* hp4 = (const float4*)hp;
        float4 v0 = hp4[0], v1 = hp4[1], v2 = hp4[2], v3 = hp4[3];
        float hv[16];
        hv[0]=v0.x; hv[1]=v0.y; hv[2]=v0.z; hv[3]=v0.w;
        hv[4]=v1.x; hv[5]=v1.y; hv[6]=v1.z; hv[7]=v1.w;
        hv[8]=v2.x; hv[9]=v2.y; hv[10]=v2.z; hv[11]=v2.w;
        hv[12]=v3.x; hv[13]=v3.y; hv[14]=v3.z; hv[15]=v3.w;
        #pragma unroll
        for (int i = 0; i < 16; ++i) {
            const int e = eb + i;
            const float val = s_o[m * SO + e] + b2[e] + hv[i];
            out[(((size_t)b * E_ + e) * R_ + r) * C_ + c] = val;
        }
    }
}

extern "C" void kernel_launch(void* const* d_in, const int* in_sizes, int n_in,
                              void* d_out, int out_size, void* d_ws, size_t ws_size,
                              hipStream_t stream) {
    const float* x      = (const float*)d_in[0];
    const float* row_wq = (const float*)d_in[1];
    const float* row_bq = (const float*)d_in[2];
    const float* row_wk = (const float*)d_in[3];
    const float* row_bk = (const float*)d_in[4];
    const float* row_wv = (const float*)d_in[5];
    const float* row_bv = (const float*)d_in[6];
    const float* row_wo = (const float*)d_in[7];
    const float* row_bo = (const float*)d_in[8];
    const float* col_wq = (const float*)d_in[9];
    const float* col_bq = (const float*)d_in[10];
    const float* col_wk = (const float*)d_in[11];
    const float* col_bk = (const float*)d_in[12];
    const float* col_wv = (const float*)d_in[13];
    const float* col_bv = (const float*)d_in[14];
    const float* col_wo = (const float*)d_in[15];
    const float* col_bo = (const float*)d_in[16];
    const float* rn_g   = (const float*)d_in[17];
    const float* rn_b   = (const float*)d_in[18];
    const float* cn_g   = (const float*)d_in[19];
    const float* cn_b   = (const float*)d_in[20];
    const float* fn_g   = (const float*)d_in[21];
    const float* fn_b   = (const float*)d_in[22];
    const float* w1     = (const float*)d_in[23];
    const float* b1     = (const float*)d_in[24];
    const float* w2     = (const float*)d_in[25];
    const float* b2     = (const float*)d_in[26];

    const size_t need = (size_t)B_ * C_ * R_ * E_ * sizeof(float);
    if (ws_size < need) return;
    float* hbuf = (float*)d_ws;

    const bool prep = (ws_size >= need + 2 * 16384 * sizeof(short) + 256);
    short* w1b = (short*)((char*)d_ws + need);
    short* w2b = w1b + 16384;

    row_attn<<<dim3(R_, B_), 256, 0, stream>>>(
        x, row_wq, row_bq, row_wk, row_bk, row_wv, row_bv, row_wo, row_bo,
        rn_g, rn_b, hbuf);
    col_attn<<<dim3(C_, B_), 256, 0, stream>>>(
        hbuf, col_wq, col_bq, col_wk, col_bk, col_wv, col_bv, col_wo, col_bo,
        cn_g, cn_b);
    if (prep) {
        prep_weights<<<128, 256, 0, stream>>>(w1, w2, w1b, w2b);
        ffn_mfma<true><<<B_ * R_ * 8, 256, 0, stream>>>(
            hbuf, fn_g, fn_b, w1, w1b, b1, w2, w2b, b2, (float*)d_out);
    } else {
        ffn_mfma<false><<<B_ * R_ * 8, 256, 0, stream>>>(
            hbuf, fn_g, fn_b, w1, w1b, b1, w2, w2b, b2, (float*)d_out);
    }
}

// Round 8
// 1342.711 us; speedup vs baseline: 1.2964x; 1.0295x over previous
//
#include <hip/hip_runtime.h>
#include <cmath>

#define E_ 64
#define H_ 4
#define B_ 2
#define R_ 1225
#define C_ 512
#define EPS 1e-5f

__device__ __forceinline__ float elu1(float a) { return a > 0.f ? a + 1.f : __expf(a); }

typedef float f32x4 __attribute__((ext_vector_type(4)));
typedef short bf16x8 __attribute__((ext_vector_type(8)));
typedef short bf16x4 __attribute__((ext_vector_type(4)));

__device__ __forceinline__ unsigned short f2bf(float f) {
    union { float f; unsigned u; } c; c.f = f;
    unsigned u = c.u + 0x7FFFu + ((c.u >> 16) & 1u);   // RNE
    return (unsigned short)(u >> 16);
}

__device__ __forceinline__ float bf2f(unsigned short s) {
    union { unsigned u; float f; } c; c.u = ((unsigned)s) << 16;
    return c.f;
}

__device__ __forceinline__ bf16x8 pack8(float4 a, float4 b) {
    bf16x8 r;
    r[0] = (short)f2bf(a.x); r[1] = (short)f2bf(a.y);
    r[2] = (short)f2bf(a.z); r[3] = (short)f2bf(a.w);
    r[4] = (short)f2bf(b.x); r[5] = (short)f2bf(b.y);
    r[6] = (short)f2bf(b.z); r[7] = (short)f2bf(b.w);
    return r;
}

// tanh-approx GELU in sigmoid form (max dev ~3e-4 vs exact-erf)
__device__ __forceinline__ float gelu_fast(float a) {
    const float u = a * (-1.5957691216057308f - 0.0713548162726009f * a * a);
    return a / (1.f + __expf(u));
}

#define SX 264   // LDS row stride (256+8) in bf16

// ---------------------------------------------------------------------------
// Kernel A v3: row attention. Phase A is now a cooperative fully-coalesced
// float4 load of the (64e x 256c) x-tile -> bf16 -> s_xT (each wave-inst
// reads 1KB contiguous of one e-row). Phase B computes per-position LN
// stats + q/k from the LDS column (64 ds_read_u16, 2 lanes/bank = free).
// Phase E (exact fp32 strided re-read, L2/L3-hot) and h-write unchanged.
// ---------------------------------------------------------------------------
__global__ __launch_bounds__(256, 3) void row_attn(
    const float* __restrict__ x,
    const float* __restrict__ wq, const float* __restrict__ bq,
    const float* __restrict__ wk, const float* __restrict__ bk,
    const float* __restrict__ wv, const float* __restrict__ bv,
    const float* __restrict__ wo, const float* __restrict__ bo,
    const float* __restrict__ lng, const float* __restrict__ lnb,
    float* __restrict__ hout)
{
    const int r = blockIdx.x;
    const int b = blockIdx.y;
    const int t = threadIdx.x;
    const int w = t >> 6;
    const int l = t & 63;
    const int lr = l & 15;
    const int lq = l >> 4;

    __shared__ short s_xT[E_][SX];     // raw x (bf16), [e][pos-in-tile]
    __shared__ short s_kb[4][SX];      // k*rstd, bf16
    __shared__ float s_u[H_][E_];
    __shared__ float s_ktv[E_];
    __shared__ float s_wok[E_][H_];
    __shared__ float s_qm[H_];
    __shared__ float s_sk[H_];
    __shared__ float s_S1[H_];
    __shared__ float red_q[4][H_];
    __shared__ float red_k[4][H_];
    __shared__ float red_k2[4][H_];
    __shared__ float s_cst[16];        // WgQ[4] CQ[4] WgK[4] CK[4]

    // block-uniform constants
    if (t < 16) {
        const int h = t & 3;
        const int kind = t >> 2;                    // 0 WgQ, 1 CQ, 2 WgK, 3 CK
        const float* wm = (kind < 2) ? wq : wk;
        const float* vm = (kind & 1) ? lnb : lng;
        float acc = 0.f;
        for (int e = 0; e < E_; ++e) acc += wm[h * E_ + e] * vm[e];
        s_cst[t] = acc;
    }
    __syncthreads();

    const size_t RC = (size_t)R_ * C_;
    const float* xbase = x + (size_t)b * E_ * RC + (size_t)r * C_;

    float aq[H_]  = {0.f, 0.f, 0.f, 0.f};
    float ak[H_]  = {0.f, 0.f, 0.f, 0.f};
    float ak2[H_] = {0.f, 0.f, 0.f, 0.f};
    float qs[2][H_];
    f32x4 uacc; uacc[0] = uacc[1] = uacc[2] = uacc[3] = 0.f;

    #pragma unroll 1
    for (int it = 0; it < 2; ++it) {
        // ---- phase A: cooperative coalesced tile load -> bf16 -> s_xT ----
        // wave-inst j: one e-row (e = j*4 + w), lanes cover 256 c (1KB contig)
        {
            const float* xt = xbase + it * 256;
            #pragma unroll
            for (int j = 0; j < 16; ++j) {
                const int e = j * 4 + w;
                const float4 v = *reinterpret_cast<const float4*>(
                    xt + (size_t)e * RC + l * 4);
                bf16x4 pk;
                pk[0] = (short)f2bf(v.x); pk[1] = (short)f2bf(v.y);
                pk[2] = (short)f2bf(v.z); pk[3] = (short)f2bf(v.w);
                *reinterpret_cast<bf16x4*>(&s_xT[e][l * 4]) = pk;
            }
        }
        __syncthreads();

        // ---- phase B: per-position LN stats + q/k from LDS column --------
        {
            float s = 0.f, ss = 0.f;
            float dq[H_] = {0.f, 0.f, 0.f, 0.f};
            float dk[H_] = {0.f, 0.f, 0.f, 0.f};
            #pragma unroll
            for (int e = 0; e < E_; ++e) {
                const float xv = bf2f((unsigned short)s_xT[e][t]);
                s += xv; ss += xv * xv;
                const float t1 = lng[e] * xv;
                #pragma unroll
                for (int h = 0; h < H_; ++h) { dq[h] += wq[h * E_ + e] * t1; dk[h] += wk[h * E_ + e] * t1; }
            }
            const float mu = s * (1.f / E_);
            const float rstd = rsqrtf(ss * (1.f / E_) - mu * mu + EPS);
            const float mr = mu * rstd;
            #pragma unroll
            for (int h = 0; h < H_; ++h) {
                const float qv = elu1(rstd * dq[h] - mr * s_cst[h]     + s_cst[4 + h]  + bq[h]);
                const float kv = elu1(rstd * dk[h] - mr * s_cst[8 + h] + s_cst[12 + h] + bk[h]);
                qs[it][h] = qv;
                aq[h] += qv; ak[h] += kv; ak2[h] += kv * mr;
                s_kb[h][t] = (short)f2bf(kv * rstd);
            }
        }
        __syncthreads();

        // ---- MFMA: u += K^T x X -----------------------------------------
        #pragma unroll
        for (int ks = 0; ks < 8; ++ks) {
            bf16x8 af;
            #pragma unroll
            for (int i = 0; i < 8; ++i) af[i] = 0;
            if (lr < 4) af = *reinterpret_cast<const bf16x8*>(&s_kb[lr][ks * 32 + lq * 8]);
            const bf16x8 bf = *reinterpret_cast<const bf16x8*>(&s_xT[w * 16 + lr][ks * 32 + lq * 8]);
            uacc = __builtin_amdgcn_mfma_f32_16x16x32_bf16(af, bf, uacc, 0, 0, 0);
        }
        __syncthreads();
    }

    // reductions of sum_q, sum_k, sum k*rstd*mu
    #pragma unroll
    for (int h = 0; h < H_; ++h) {
        #pragma unroll
        for (int off = 32; off; off >>= 1) {
            aq[h] += __shfl_xor(aq[h], off, 64);
            ak[h] += __shfl_xor(ak[h], off, 64);
            ak2[h] += __shfl_xor(ak2[h], off, 64);
        }
    }
    if (l == 0) {
        #pragma unroll
        for (int h = 0; h < H_; ++h) { red_q[w][h] = aq[h]; red_k[w][h] = ak[h]; red_k2[w][h] = ak2[h]; }
    }
    __syncthreads();
    if (t < H_) {
        float sq = 0.f, sk = 0.f, s1 = 0.f;
        #pragma unroll
        for (int w2 = 0; w2 < 4; ++w2) { sq += red_q[w2][t]; sk += red_k[w2][t]; s1 += red_k2[w2][t]; }
        s_qm[t] = sq * (1.f / C_);
        s_sk[t] = sk;
        s_S1[t] = s1;
    }
    __syncthreads();
    // u[h][e] = g[e]*(M1 - S1[h]) + lb[e]*sk[h]
    if (lq == 0) {
        const int e = w * 16 + lr;
        #pragma unroll
        for (int i = 0; i < 4; ++i)
            s_u[i][e] = lng[e] * (uacc[i] - s_S1[i]) + lnb[e] * s_sk[i];
    }
    __syncthreads();
    if (t < E_) {
        const int h = t >> 4;
        float acc = 0.f;
        #pragma unroll
        for (int e = 0; e < E_; ++e) acc += wv[t * E_ + e] * s_u[h][e];
        s_ktv[t] = acc / s_sk[h] + bv[t];
    }
    __syncthreads();
    if (t < E_) {
        #pragma unroll
        for (int h = 0; h < H_; ++h) {
            float acc = 0.f;
            #pragma unroll
            for (int d = 0; d < 16; ++d) acc += wo[t * E_ + h * 16 + d] * s_ktv[h * 16 + d];
            s_wok[t][h] = acc;
        }
    }
    __syncthreads();

    // ---- phase E: residual (exact fp32, cache-hot re-read) + h write ----
    #pragma unroll 1
    for (int it = 0; it < 2; ++it) {
        const int c = it * 256 + t;
        const float* xp = xbase + c;
        float qn[H_];
        #pragma unroll
        for (int h = 0; h < H_; ++h) qn[h] = qs[it][h] / s_qm[h];
        float* hp = hout + ((size_t)(b * C_ + c) * R_ + r) * E_;
        #pragma unroll 4
        for (int e4 = 0; e4 < 16; ++e4) {
            float4 o;
            float* ov = (float*)&o;
            #pragma unroll
            for (int i = 0; i < 4; ++i) {
                const int e = e4 * 4 + i;
                float tt = bo[e];
                #pragma unroll
                for (int h = 0; h < H_; ++h) tt += qn[h] * s_wok[e][h];
                ov[i] = xp[(size_t)e * RC] + tt;
            }
            *reinterpret_cast<float4*>(hp + e4 * 4) = o;
        }
    }
}

// ---------------------------------------------------------------------------
// Kernel B: col attention (unchanged from round 7).
// ---------------------------------------------------------------------------
__global__ __launch_bounds__(256, 3) void col_attn(
    float* __restrict__ hbuf,
    const float* __restrict__ wq, const float* __restrict__ bq,
    const float* __restrict__ wk, const float* __restrict__ bk,
    const float* __restrict__ wv, const float* __restrict__ bv,
    const float* __restrict__ wo, const float* __restrict__ bo,
    const float* __restrict__ lng, const float* __restrict__ lnb)
{
    const int c = blockIdx.x;
    const int b = blockIdx.y;
    const int t = threadIdx.x;
    const int w = t >> 6;
    const int l = t & 63;
    const int lr = l & 15;
    const int lq = l >> 4;

    __shared__ short s_xT[E_][SX];
    __shared__ short s_kb[4][SX];
    __shared__ float s_u[H_][E_];
    __shared__ float s_ktv[E_];
    __shared__ float s_wok[E_][H_];
    __shared__ float s_qm[H_];
    __shared__ float s_sk[H_];
    __shared__ float s_S1[H_];
    __shared__ float red_q[4][H_];
    __shared__ float red_k[4][H_];
    __shared__ float red_k2[4][H_];
    __shared__ float s_cst[16];

    if (t < 16) {
        const int h = t & 3;
        const int kind = t >> 2;
        const float* wm = (kind < 2) ? wq : wk;
        const float* vm = (kind & 1) ? lnb : lng;
        float acc = 0.f;
        for (int e = 0; e < E_; ++e) acc += wm[h * E_ + e] * vm[e];
        s_cst[t] = acc;
    }
    __syncthreads();

    float* hp0 = hbuf + (size_t)(b * C_ + c) * R_ * E_;

    float aq[H_]  = {0.f, 0.f, 0.f, 0.f};
    float ak[H_]  = {0.f, 0.f, 0.f, 0.f};
    float ak2[H_] = {0.f, 0.f, 0.f, 0.f};
    unsigned qs_pk[5][2];
    f32x4 uacc; uacc[0] = uacc[1] = uacc[2] = uacc[3] = 0.f;

    #pragma unroll 1
    for (int it = 0; it < 5; ++it) {
        const int rr = it * 256 + t;
        if (rr < R_) {
            const float4* pp4 = (const float4*)(hp0 + (size_t)rr * E_);
            float s = 0.f, ss = 0.f;
            float dq[H_] = {0.f, 0.f, 0.f, 0.f};
            float dk[H_] = {0.f, 0.f, 0.f, 0.f};
            #pragma unroll 4
            for (int e4 = 0; e4 < 16; ++e4) {
                const float4 v4 = pp4[e4];
                const float* vv = (const float*)&v4;
                #pragma unroll
                for (int i = 0; i < 4; ++i) {
                    const int e = e4 * 4 + i;
                    const float xv = vv[i];
                    s += xv; ss += xv * xv;
                    const float t1 = lng[e] * xv;
                    #pragma unroll
                    for (int h = 0; h < H_; ++h) { dq[h] += wq[h * E_ + e] * t1; dk[h] += wk[h * E_ + e] * t1; }
                    s_xT[e][t] = (short)f2bf(xv);
                }
            }
            const float mu = s * (1.f / E_);
            const float rstd = rsqrtf(ss * (1.f / E_) - mu * mu + EPS);
            const float mr = mu * rstd;
            float qv[H_];
            #pragma unroll
            for (int h = 0; h < H_; ++h) {
                qv[h] = elu1(rstd * dq[h] - mr * s_cst[h]     + s_cst[4 + h]  + bq[h]);
                const float kv = elu1(rstd * dk[h] - mr * s_cst[8 + h] + s_cst[12 + h] + bk[h]);
                aq[h] += qv[h]; ak[h] += kv; ak2[h] += kv * mr;
                s_kb[h][t] = (short)f2bf(kv * rstd);
            }
            qs_pk[it][0] = ((unsigned)f2bf(qv[1]) << 16) | f2bf(qv[0]);
            qs_pk[it][1] = ((unsigned)f2bf(qv[3]) << 16) | f2bf(qv[2]);
        } else {
            #pragma unroll
            for (int e = 0; e < E_; ++e) s_xT[e][t] = 0;
            #pragma unroll
            for (int h = 0; h < H_; ++h) s_kb[h][t] = 0;
            qs_pk[it][0] = 0; qs_pk[it][1] = 0;
        }
        __syncthreads();
        #pragma unroll
        for (int ks = 0; ks < 8; ++ks) {
            bf16x8 af;
            #pragma unroll
            for (int i = 0; i < 8; ++i) af[i] = 0;
            if (lr < 4) af = *reinterpret_cast<const bf16x8*>(&s_kb[lr][ks * 32 + lq * 8]);
            const bf16x8 bf = *reinterpret_cast<const bf16x8*>(&s_xT[w * 16 + lr][ks * 32 + lq * 8]);
            uacc = __builtin_amdgcn_mfma_f32_16x16x32_bf16(af, bf, uacc, 0, 0, 0);
        }
        __syncthreads();
    }

    #pragma unroll
    for (int h = 0; h < H_; ++h) {
        #pragma unroll
        for (int off = 32; off; off >>= 1) {
            aq[h] += __shfl_xor(aq[h], off, 64);
            ak[h] += __shfl_xor(ak[h], off, 64);
            ak2[h] += __shfl_xor(ak2[h], off, 64);
        }
    }
    if (l == 0) {
        #pragma unroll
        for (int h = 0; h < H_; ++h) { red_q[w][h] = aq[h]; red_k[w][h] = ak[h]; red_k2[w][h] = ak2[h]; }
    }
    __syncthreads();
    if (t < H_) {
        float sq = 0.f, sk = 0.f, s1 = 0.f;
        #pragma unroll
        for (int w2 = 0; w2 < 4; ++w2) { sq += red_q[w2][t]; sk += red_k[w2][t]; s1 += red_k2[w2][t]; }
        s_qm[t] = sq * (1.f / R_);
        s_sk[t] = sk;
        s_S1[t] = s1;
    }
    __syncthreads();
    if (lq == 0) {
        const int e = w * 16 + lr;
        #pragma unroll
        for (int i = 0; i < 4; ++i)
            s_u[i][e] = lng[e] * (uacc[i] - s_S1[i]) + lnb[e] * s_sk[i];
    }
    __syncthreads();
    if (t < E_) {
        const int h = t >> 4;
        float acc = 0.f;
        #pragma unroll
        for (int e = 0; e < E_; ++e) acc += wv[t * E_ + e] * s_u[h][e];
        s_ktv[t] = acc / s_sk[h] + bv[t];
    }
    __syncthreads();
    if (t < E_) {
        #pragma unroll
        for (int h = 0; h < H_; ++h) {
            float acc = 0.f;
            #pragma unroll
            for (int d = 0; d < 16; ++d) acc += wo[t * E_ + h * 16 + d] * s_ktv[h * 16 + d];
            s_wok[t][h] = acc;
        }
    }
    __syncthreads();

    #pragma unroll 1
    for (int it = 0; it < 5; ++it) {
        const int rr = it * 256 + t;
        if (rr >= R_) continue;
        float qn[H_];
        qn[0] = bf2f((unsigned short)(qs_pk[it][0] & 0xFFFF)) / s_qm[0];
        qn[1] = bf2f((unsigned short)(qs_pk[it][0] >> 16))    / s_qm[1];
        qn[2] = bf2f((unsigned short)(qs_pk[it][1] & 0xFFFF)) / s_qm[2];
        qn[3] = bf2f((unsigned short)(qs_pk[it][1] >> 16))    / s_qm[3];
        float* pp = hp0 + (size_t)rr * E_;
        #pragma unroll 4
        for (int e4 = 0; e4 < 16; ++e4) {
            const float4 v4 = *reinterpret_cast<const float4*>(pp + e4 * 4);
            const float* hv4 = (const float*)&v4;
            float4 o;
            float* ov = (float*)&o;
            #pragma unroll
            for (int i = 0; i < 4; ++i) {
                const int e = e4 * 4 + i;
                float tt = bo[e];
                #pragma unroll
                for (int h = 0; h < H_; ++h) tt += qn[h] * s_wok[e][h];
                ov[i] = hv4[i] + tt;
            }
            *reinterpret_cast<float4*>(pp + e4 * 4) = o;
        }
    }
}

// ---------------------------------------------------------------------------
// prep_weights: fp32 -> bf16 for w1/w2.
// ---------------------------------------------------------------------------
__global__ __launch_bounds__(256) void prep_weights(
    const float* __restrict__ w1, const float* __restrict__ w2,
    short* __restrict__ w1b, short* __restrict__ w2b)
{
    const int i = blockIdx.x * 256 + threadIdx.x;
    if (i < 16384) w1b[i] = (short)f2bf(w1[i]);
    else           w2b[i - 16384] = (short)f2bf(w2[i - 16384]);
}

// ---------------------------------------------------------------------------
// Kernel C: MFMA bf16 FFN (unchanged).
// ---------------------------------------------------------------------------
#define SA 72
#define SG 264
#define SO 65

template <bool PREP>
__global__ __launch_bounds__(256) void ffn_mfma(
    const float* __restrict__ hbuf,
    const float* __restrict__ lng, const float* __restrict__ lnb,
    const float* __restrict__ w1, const short* __restrict__ w1b,
    const float* __restrict__ b1,
    const float* __restrict__ w2, const short* __restrict__ w2b,
    const float* __restrict__ b2,
    float* __restrict__ out)
{
    __shared__ __align__(16) char smem[33792 + 16640];
    short* s_g = (short*)smem;
    short* s_a = (short*)(smem + 33792);
    float* s_o = (float*)(smem + 33792);

    const int t = threadIdx.x;
    const int w = t >> 6;
    const int l = t & 63;
    const int lr = l & 15;
    const int lq = l >> 4;

    const int bid = blockIdx.x;
    const int cb  = bid & 7;
    const int rem = bid >> 3;
    const int r   = rem % R_;
    const int b   = rem / R_;
    const int c0  = cb * 64;

    {
        const int m  = t >> 2;
        const int qi = t & 3;
        const float* hp = hbuf + ((size_t)(b * C_ + c0 + m) * R_ + r) * E_ + qi * 16;
        const float4* hp4 = (const float4*)hp;
        float4 v0 = hp4[0], v1 = hp4[1], v2 = hp4[2], v3 = hp4[3];
        float hv[16];
        hv[0]=v0.x; hv[1]=v0.y; hv[2]=v0.z; hv[3]=v0.w;
        hv[4]=v1.x; hv[5]=v1.y; hv[6]=v1.z; hv[7]=v1.w;
        hv[8]=v2.x; hv[9]=v2.y; hv[10]=v2.z; hv[11]=v2.w;
        hv[12]=v3.x; hv[13]=v3.y; hv[14]=v3.z; hv[15]=v3.w;
        float s = 0.f, ss = 0.f;
        #pragma unroll
        for (int i = 0; i < 16; ++i) { s += hv[i]; ss += hv[i] * hv[i]; }
        s  += __shfl_xor(s, 1, 64);  s  += __shfl_xor(s, 2, 64);
        ss += __shfl_xor(ss, 1, 64); ss += __shfl_xor(ss, 2, 64);
        const float mu = s * (1.f / 64.f);
        const float rstd = rsqrtf(ss * (1.f / 64.f) - mu * mu + EPS);
        bf16x8 o0, o1;
        #pragma unroll
        for (int i = 0; i < 8; ++i) {
            const int e = qi * 16 + i;
            o0[i] = (short)f2bf((hv[i] - mu) * rstd * lng[e] + lnb[e]);
        }
        #pragma unroll
        for (int i = 0; i < 8; ++i) {
            const int e = qi * 16 + 8 + i;
            o1[i] = (short)f2bf((hv[8 + i] - mu) * rstd * lng[e] + lnb[e]);
        }
        *reinterpret_cast<bf16x8*>(&s_a[m * SA + qi * 16])     = o0;
        *reinterpret_cast<bf16x8*>(&s_a[m * SA + qi * 16 + 8]) = o1;
    }
    __syncthreads();

    {
        bf16x8 bfr[4][2];
        #pragma unroll
        for (int mt = 0; mt < 4; ++mt)
            #pragma unroll
            for (int ks = 0; ks < 2; ++ks)
                bfr[mt][ks] = *reinterpret_cast<const bf16x8*>(
                    &s_a[(mt * 16 + lr) * SA + ks * 32 + lq * 8]);

        #pragma unroll
        for (int nn = 0; nn < 4; ++nn) {
            const int jt = w * 4 + nn;
            bf16x8 afr[2];
            if (PREP) {
                #pragma unroll
                for (int ks = 0; ks < 2; ++ks)
                    afr[ks] = *reinterpret_cast<const bf16x8*>(
                        w1b + (size_t)(jt * 16 + lr) * 64 + ks * 32 + lq * 8);
            } else {
                #pragma unroll
                for (int ks = 0; ks < 2; ++ks) {
                    const float4* wp = (const float4*)(w1 + (size_t)(jt * 16 + lr) * 64 + ks * 32 + lq * 8);
                    afr[ks] = pack8(wp[0], wp[1]);
                }
            }
            f32x4 acc[4];
            #pragma unroll
            for (int mt = 0; mt < 4; ++mt) { acc[mt][0]=0.f; acc[mt][1]=0.f; acc[mt][2]=0.f; acc[mt][3]=0.f; }
            #pragma unroll
            for (int ks = 0; ks < 2; ++ks)
                #pragma unroll
                for (int mt = 0; mt < 4; ++mt)
                    acc[mt] = __builtin_amdgcn_mfma_f32_16x16x32_bf16(afr[ks], bfr[mt][ks], acc[mt], 0, 0, 0);

            const float4 b1v = *reinterpret_cast<const float4*>(&b1[jt * 16 + lq * 4]);
            const float* b1p = (const float*)&b1v;
            #pragma unroll
            for (int mt = 0; mt < 4; ++mt) {
                const int m = mt * 16 + lr;
                bf16x4 pk;
                #pragma unroll
                for (int i = 0; i < 4; ++i) {
                    const float aa = acc[mt][i] + b1p[i];
                    pk[i] = (short)f2bf(gelu_fast(aa));
                }
                *reinterpret_cast<bf16x4*>(&s_g[m * SG + jt * 16 + lq * 4]) = pk;
            }
        }
    }
    __syncthreads();

    {
        f32x4 acc2[4];
        #pragma unroll
        for (int mt = 0; mt < 4; ++mt) { acc2[mt][0]=0.f; acc2[mt][1]=0.f; acc2[mt][2]=0.f; acc2[mt][3]=0.f; }
        const int n = w * 16 + lr;
        #pragma unroll
        for (int ks = 0; ks < 8; ++ks) {
            bf16x8 bfr;
            if (PREP) {
                bfr = *reinterpret_cast<const bf16x8*>(w2b + (size_t)n * 256 + ks * 32 + lq * 8);
            } else {
                const float4* wp = (const float4*)(w2 + (size_t)n * 256 + ks * 32 + lq * 8);
                bfr = pack8(wp[0], wp[1]);
            }
            #pragma unroll
            for (int mt = 0; mt < 4; ++mt) {
                const bf16x8 af = *reinterpret_cast<const bf16x8*>(
                    &s_g[(mt * 16 + lr) * SG + ks * 32 + lq * 8]);
                acc2[mt] = __builtin_amdgcn_mfma_f32_16x16x32_bf16(af, bfr, acc2[mt], 0, 0, 0);
            }
        }
        #pragma unroll
        for (int mt = 0; mt < 4; ++mt)
            #pragma unroll
            for (int i = 0; i < 4; ++i)
                s_o[(mt * 16 + lq * 4 + i) * SO + n] = acc2[mt][i];
    }
    __syncthreads();

    {
        const int m  = t & 63;
        const int eb = (t >> 6) * 16;
        const int c  = c0 + m;
        const float* hp = hbuf + ((size_t)(b * C_ + c) * R_ + r) * E_ + eb;
        const float4* hp4 = (const float4*)hp;
        float4 v0 = hp4[0], v1 = hp4[1], v2 = hp4[2], v3 = hp4[3];
        float hv[16];
        hv[0]=v0.x; hv[1]=v0.y; hv[2]=v0.z; hv[3]=v0.w;
        hv[4]=v1.x; hv[5]=v1.y; hv[6]=v1.z; hv[7]=v1.w;
        hv[8]=v2.x; hv[9]=v2.y; hv[10]=v2.z; hv[11]=v2.w;
        hv[12]=v3.x; hv[13]=v3.y; hv[14]=v3.z; hv[15]=v3.w;
        #pragma unroll
        for (int i = 0; i < 16; ++i) {
            const int e = eb + i;
            const float val = s_o[m * SO + e] + b2[e] + hv[i];
            out[(((size_t)b * E_ + e) * R_ + r) * C_ + c] = val;
        }
    }
}

extern "C" void kernel_launch(void* const* d_in, const int* in_sizes, int n_in,
                              void* d_out, int out_size, void* d_ws, size_t ws_size,
                              hipStream_t stream) {
    const float* x      = (const float*)d_in[0];
    const float* row_wq = (const float*)d_in[1];
    const float* row_bq = (const float*)d_in[2];
    const float* row_wk = (const float*)d_in[3];
    const float* row_bk = (const float*)d_in[4];
    const float* row_wv = (const float*)d_in[5];
    const float* row_bv = (const float*)d_in[6];
    const float* row_wo = (const float*)d_in[7];
    const float* row_bo = (const float*)d_in[8];
    const float* col_wq = (const float*)d_in[9];
    const float* col_bq = (const float*)d_in[10];
    const float* col_wk = (const float*)d_in[11];
    const float* col_bk = (const float*)d_in[12];
    const float* col_wv = (const float*)d_in[13];
    const float* col_bv = (const float*)d_in[14];
    const float* col_wo = (const float*)d_in[15];
    const float* col_bo = (const float*)d_in[16];
    const float* rn_g   = (const float*)d_in[17];
    const float* rn_b   = (const float*)d_in[18];
    const float* cn_g   = (const float*)d_in[19];
    const float* cn_b   = (const float*)d_in[20];
    const float* fn_g   = (const float*)d_in[21];
    const float* fn_b   = (const float*)d_in[22];
    const float* w1     = (const float*)d_in[23];
    const float* b1     = (const float*)d_in[24];
    const float* w2     = (const float*)d_in[25];
    const float* b2     = (const float*)d_in[26];

    const size_t need = (size_t)B_ * C_ * R_ * E_ * sizeof(float);
    if (ws_size < need) return;
    float* hbuf = (float*)d_ws;

    const bool prep = (ws_size >= need + 2 * 16384 * sizeof(short) + 256);
    short* w1b = (short*)((char*)d_ws + need);
    short* w2b = w1b + 16384;

    row_attn<<<dim3(R_, B_), 256, 0, stream>>>(
        x, row_wq, row_bq, row_wk, row_bk, row_wv, row_bv, row_wo, row_bo,
        rn_g, rn_b, hbuf);
    col_attn<<<dim3(C_, B_), 256, 0, stream>>>(
        hbuf, col_wq, col_bq, col_wk, col_bk, col_wv, col_bv, col_wo, col_bo,
        cn_g, cn_b);
    if (prep) {
        prep_weights<<<128, 256, 0, stream>>>(w1, w2, w1b, w2b);
        ffn_mfma<true><<<B_ * R_ * 8, 256, 0, stream>>>(
            hbuf, fn_g, fn_b, w1, w1b, b1, w2, w2b, b2, (float*)d_out);
    } else {
        ffn_mfma<false><<<B_ * R_ * 8, 256, 0, stream>>>(
            hbuf, fn_g, fn_b, w1, w1b, b1, w2, w2b, b2, (float*)d_out);
    }
}